// Round 9
// baseline (917.256 us; speedup 1.0000x reference)
//
#include <hip/hip_runtime.h>

#define NN 50000   // nodes
#define NE 600000  // edges
#define DF 128     // features
#define NB 16384   // pair batch

__device__ __forceinline__ float bf2f(unsigned short u){
  return __uint_as_float(((unsigned int)u) << 16);
}
__device__ __forceinline__ unsigned short f2bf(float x){
  unsigned int b = __float_as_uint(x);
  return (unsigned short)((b + 0x7FFFu + ((b >> 16) & 1u)) >> 16);
}

// Original template symbol (defined, never launched).
__global__ void GraphSAGE_8504035246140_kernel(){ }

// ---- zero-init ----
__global__ void k_zero_i(int* p, int n){
  int i = blockIdx.x * 256 + threadIdx.x;
  if (i < n) p[i] = 0;
}
__global__ void k_zero_f(float* p, int n){
  int i = blockIdx.x * 256 + threadIdx.x;
  if (i < n) p[i] = 0.f;
}

// ---- h (fp32) -> bf16 u16 working copy ----
__global__ void k_cvt_h(const float* src, unsigned short* dst, int n){
  int i = blockIdx.x * 256 + threadIdx.x;
  if (i < n) dst[i] = f2bf(src[i]);
}

// ---- CSR build ----
__global__ void k_hist(const int* dst, int* cnt){
  int e = blockIdx.x * 256 + threadIdx.x;
  if (e < NE) atomicAdd(&cnt[dst[e]], 1);
}
__global__ void k_deginv(const int* cnt, float* dinv){
  int n = blockIdx.x * 256 + threadIdx.x;
  if (n < NN) dinv[n] = 1.0f / fmaxf((float)cnt[n], 1.0f);
}
__global__ void k_scan(const int* cnt, int* rp){
  __shared__ int lds[256];
  int t = threadIdx.x;
  const int CH = (NN + 255) / 256; // 196
  int base = t * CH;
  int s = 0;
  for (int i = 0; i < CH; ++i){ int idx = base + i; if (idx < NN) s += cnt[idx]; }
  lds[t] = s; __syncthreads();
  for (int off = 1; off < 256; off <<= 1){
    int v = (t >= off) ? lds[t - off] : 0;
    __syncthreads();
    lds[t] += v;
    __syncthreads();
  }
  int run = (t == 0) ? 0 : lds[t - 1];
  for (int i = 0; i < CH; ++i){
    int idx = base + i;
    if (idx < NN){ rp[idx] = run; run += cnt[idx]; }
  }
  if (t == 0) rp[NN] = lds[255];
}
__global__ void k_scatter(const int* src, const int* dst,
                          const int* rp, int* fill, int* perm){
  int e = blockIdx.x * 256 + threadIdx.x;
  if (e < NE){
    int d = dst[e];
    int pos = atomicAdd(&fill[d], 1);
    perm[rp[d] + pos] = src[e];
  }
}

// ---- mean aggregation: one 128-thread block per node ----
__global__ void k_agg(const unsigned short* hb, const int* rp, const int* perm,
                      const float* dinv, unsigned short* aggb){
  int n = blockIdx.x, c = threadIdx.x;
  int s = rp[n], e = rp[n + 1];
  float acc = 0.f;
  for (int i = s; i < e; ++i){
    int u = perm[i];
    acc += bf2f(hb[(size_t)u * DF + c]);
  }
  aggb[(size_t)n * DF + c] = f2bf(acc * dinv[n]);
}

// ---- layer GEMM: hout = relu(h@Ws + agg@Wn + b); fp32 weights bf16-packed
// into 32 KiB LDS. grid 1024, col-half split.
__global__ void k_layer_gemm(const unsigned short* hb, const unsigned short* aggb,
                             const float* Ws, const float* Wn,
                             const float* bias, unsigned short* hout){
  __shared__ unsigned int WL[DF * 64];
  int t = threadIdx.x;                 // 256
  int ch = blockIdx.x & 1;
  for (int i = t; i < DF * 64; i += 256){
    int k = i >> 6, cl = i & 63;
    int gi = k * DF + ch * 64 + cl;
    WL[i] = (unsigned int)f2bf(Ws[gi]) | ((unsigned int)f2bf(Wn[gi]) << 16);
  }
  __syncthreads();
  int cl = t & 63, rr = t >> 6;
  int c = ch * 64 + cl;
  float bb = bias[c];
  int q0 = (int)(blockIdx.x >> 1);
  int qs = (int)(gridDim.x >> 1);
  for (int q = q0; q < NN / 4; q += qs){
    int r = q * 4 + rr;
    const unsigned short* hr = hb   + (size_t)r * DF;
    const unsigned short* ar = aggb + (size_t)r * DF;
    float acc = bb;
    for (int k = 0; k < DF; ++k){
      unsigned int w = WL[k * 64 + cl];
      acc = fmaf(bf2f(hr[k]), __uint_as_float(w << 16), acc);
      acc = fmaf(bf2f(ar[k]), __uint_as_float(w & 0xffff0000u), acc);
    }
    hout[(size_t)r * DF + c] = f2bf(fmaxf(acc, 0.f));
  }
}

// ---- head pre-BN GEMM: z = [ha, hb, |ha-hb|] @ W1 + b1 (fp32 W1/b1) ----
__global__ void k_pair_gemm(const unsigned short* hb, const int* ia, const int* ib,
                            const float* W1, const float* b1, float* z){
  __shared__ float f[3 * DF];
  int r = blockIdx.x, c = threadIdx.x; // 128
  int a = ia[r], b = ib[r];
  float va = bf2f(hb[(size_t)a * DF + c]);
  float vb = bf2f(hb[(size_t)b * DF + c]);
  f[c] = va; f[c + DF] = vb; f[c + 2 * DF] = fabsf(va - vb);
  __syncthreads();
  float acc = b1[c];
  for (int k = 0; k < 3 * DF; ++k)
    acc = fmaf(f[k], W1[k * DF + c], acc);
  z[(size_t)r * DF + c] = acc;
}

// ---- per-column stats ----
__global__ void k_colstats(const float* z, float* ssum, float* ssq){
  int c = threadIdx.x; // 128
  const int RPB = NB / 256; // grid 256
  int r0 = blockIdx.x * RPB;
  float s = 0.f, s2 = 0.f;
  for (int r = r0; r < r0 + RPB; ++r){
    float v = z[(size_t)r * DF + c];
    s += v; s2 += v * v;
  }
  atomicAdd(&ssum[c], s);
  atomicAdd(&ssq[c], s2);
}
__global__ void k_finstats(const float* stats, float* mstd){
  int t = threadIdx.x; // 256
  int g = t >> 7, c = t & 127;
  float m = stats[g * 256 + c] / (float)NB;
  float v = stats[g * 256 + 128 + c] / (float)NB - m * m;
  mstd[g * 256 + c] = m;
  mstd[g * 256 + 128 + c] = 1.0f / sqrtf(v + 1e-5f);
}

// ---- normalize + relu, fp32 store into d_out ----
__global__ void k_norm(const float* z, const float* mstd,
                       const float* gamma, const float* beta, float* out){
  int i = blockIdx.x * 256 + threadIdx.x;
  if (i < NB * DF){
    int c = i & 127;
    float y = (z[i] - mstd[c]) * mstd[128 + c] * gamma[c] + beta[c];
    out[i] = fmaxf(y, 0.f);
  }
}

// ---- h_p = mmd @ W2 + b2, fp32 in/out, 128-thread block per row ----
__global__ void k_hp(const float* mmd, const float* W2,
                     const float* b2, float* hp){
  __shared__ float s0[128], s1[128];
  int r = blockIdx.x, t = threadIdx.x;
  float x = mmd[(size_t)r * DF + t];
  s0[t] = x * W2[t * 2];
  s1[t] = x * W2[t * 2 + 1];
  __syncthreads();
  for (int off = 64; off > 0; off >>= 1){
    if (t < off){ s0[t] += s0[t + off]; s1[t] += s1[t + off]; }
    __syncthreads();
  }
  if (t == 0){
    hp[r * 2]     = s0[0] + b2[0];
    hp[r * 2 + 1] = s1[0] + b2[1];
  }
}

extern "C" __attribute__((used, visibility("default")))
void kernel_launch(void* const* d_in, const int* in_sizes, int n_in,
                   void* d_out, int out_size, void* d_ws, size_t ws_size,
                   hipStream_t stream){
  const float* h_in  = (const float*)d_in[0];   // fp32 (proven R5/R7)
  const int* esrc = (const int*)d_in[1];
  const int* edst = (const int*)d_in[2];
  const int* x1   = (const int*)d_in[3];
  const int* x2   = (const int*)d_in[4];
  const int* x1t  = (const int*)d_in[5];
  const int* x2t  = (const int*)d_in[6];
  const float* Wself = (const float*)d_in[7];
  const float* Wneigh= (const float*)d_in[8];
  const float* bconv = (const float*)d_in[9];
  const float* W1    = (const float*)d_in[10];
  const float* b1    = (const float*)d_in[11];
  const float* gamma = (const float*)d_in[12];
  const float* beta  = (const float*)d_in[13];
  const float* W2    = (const float*)d_in[14];
  const float* b2    = (const float*)d_in[15];
  float* out = (float*)d_out;                   // fp32 (proven R8 bound argument)
  float* hp_out   = out;                        // [NB,2]
  float* mmd_src  = out + 2 * NB;               // [NB,DF]
  float* mmd_tar  = mmd_src + (size_t)NB * DF;  // [NB,DF]

  // ---- workspace layout (~46 MB, proven available) ----
  float* zreg  = (float*)d_ws;                       // 2*NB*DF f32
  float* z_src = zreg;
  float* z_tar = zreg + (size_t)NB * DF;
  unsigned short* aggb = (unsigned short*)zreg;      // alias (dead before z)
  float* stats = zreg + (size_t)2 * NB * DF;         // 512
  float* mstd  = stats + 512;                        // 512
  float* dinv  = mstd + 512;                         // 50,048
  int* cnt  = (int*)(dinv + 50048);                  // 50,000
  int* fill = cnt + NN;                              // 50,000
  int* rp   = fill + NN;                             // 50,016
  int* perm = rp + 50016;                            // 600,000
  unsigned short* h_c = (unsigned short*)(perm + 600000); // NN*DF u16
  unsigned short* h1b = h_c + (size_t)NN * DF;            // NN*DF u16
  unsigned short* h2b = h_c;   // alias: h_c dead after layer 0

  // zero-init via kernels only
  k_zero_i<<<(2 * NN + 255) / 256, 256, 0, stream>>>(cnt, 2 * NN);
  k_zero_f<<<2, 256, 0, stream>>>(stats, 512);

  // h -> bf16 working copy
  k_cvt_h<<<(NN * DF + 255) / 256, 256, 0, stream>>>(h_in, h_c, NN * DF);

  // CSR build
  k_hist<<<(NE + 255) / 256, 256, 0, stream>>>(edst, cnt);
  k_deginv<<<(NN + 255) / 256, 256, 0, stream>>>(cnt, dinv);
  k_scan<<<1, 256, 0, stream>>>(cnt, rp);
  k_scatter<<<(NE + 255) / 256, 256, 0, stream>>>(esrc, edst, rp, fill, perm);

  // SAGE layer 0: h_c -> h1b
  k_agg<<<NN, 128, 0, stream>>>(h_c, rp, perm, dinv, aggb);
  k_layer_gemm<<<1024, 256, 0, stream>>>(h_c, aggb, Wself, Wneigh, bconv, h1b);
  // SAGE layer 1: h1b -> h2b
  k_agg<<<NN, 128, 0, stream>>>(h1b, rp, perm, dinv, aggb);
  k_layer_gemm<<<1024, 256, 0, stream>>>(h1b, aggb, Wself + DF * DF,
                                         Wneigh + DF * DF, bconv + DF, h2b);

  // head (aggb dead; zreg reused as z_src/z_tar)
  k_pair_gemm<<<NB, 128, 0, stream>>>(h2b, x1, x2, W1, b1, z_src);
  k_pair_gemm<<<NB, 128, 0, stream>>>(h2b, x1t, x2t, W1, b1, z_tar);
  k_colstats<<<256, 128, 0, stream>>>(z_src, stats, stats + 128);
  k_colstats<<<256, 128, 0, stream>>>(z_tar, stats + 256, stats + 384);
  k_finstats<<<1, 256, 0, stream>>>(stats, mstd);
  k_norm<<<(NB * DF + 255) / 256, 256, 0, stream>>>(z_src, mstd, gamma, beta, mmd_src);
  k_norm<<<(NB * DF + 255) / 256, 256, 0, stream>>>(z_tar, mstd + 256, gamma, beta, mmd_tar);
  k_hp<<<NB, 128, 0, stream>>>(mmd_src, W2, b2, hp_out);
}

// Round 10
// 499.792 us; speedup vs baseline: 1.8353x; 1.8353x over previous
//
#include <hip/hip_runtime.h>

#define NN 50000   // nodes
#define NE 600000  // edges
#define DF 128     // features
#define NB 16384   // pair batch

typedef short bf16x8 __attribute__((ext_vector_type(8)));
typedef float f32x4 __attribute__((ext_vector_type(4)));

__device__ __forceinline__ float bf2f(unsigned short u){
  return __uint_as_float(((unsigned int)u) << 16);
}
__device__ __forceinline__ unsigned short f2bf(float x){
  unsigned int b = __float_as_uint(x);
  return (unsigned short)((b + 0x7FFFu + ((b >> 16) & 1u)) >> 16);
}

// Original template symbol (defined, never launched).
__global__ void GraphSAGE_8504035246140_kernel(){ }

// ---- zero-init ----
__global__ void k_zero_i(int* p, int n){
  int i = blockIdx.x * 256 + threadIdx.x;
  if (i < n) p[i] = 0;
}
__global__ void k_zero_f(float* p, int n){
  int i = blockIdx.x * 256 + threadIdx.x;
  if (i < n) p[i] = 0.f;
}

// ---- h (fp32) -> bf16 u16 working copy ----
__global__ void k_cvt_h(const float* src, unsigned short* dst, int n){
  int i = blockIdx.x * 256 + threadIdx.x;
  if (i < n) dst[i] = f2bf(src[i]);
}

// ---- weight swizzle into MFMA B-fragment order: B[k][n] -> [k>>3][n][k&7] ----
__global__ void k_prep(const float* Ws, const float* Wn, const float* W1,
                       unsigned short* WsB, unsigned short* WnB, unsigned short* W1B){
  int idx = blockIdx.x * 256 + threadIdx.x;   // grid 192*256 = 49152
  if (idx < 2 * DF * DF){
    int layer = idx >> 14;
    int e = idx & (DF * DF - 1);
    int k = e >> 7, n = e & 127;
    int dst = layer * DF * DF + (((k >> 3) * 128 + n) << 3) + (k & 7);
    WsB[dst] = f2bf(Ws[idx]);
    WnB[dst] = f2bf(Wn[idx]);
  }
  if (idx < 3 * DF * DF){
    int k = idx >> 7, n = idx & 127;          // W1: 384x128
    W1B[(((k >> 3) * 128 + n) << 3) + (k & 7)] = f2bf(W1[idx]);
  }
}

// ---- CSR build ----
__global__ void k_hist(const int* dst, int* cnt){
  int e = blockIdx.x * 256 + threadIdx.x;
  if (e < NE) atomicAdd(&cnt[dst[e]], 1);
}
__global__ void k_deginv(const int* cnt, float* dinv){
  int n = blockIdx.x * 256 + threadIdx.x;
  if (n < NN) dinv[n] = 1.0f / fmaxf((float)cnt[n], 1.0f);
}
__global__ void k_scan(const int* cnt, int* rp){
  __shared__ int lds[256];
  int t = threadIdx.x;
  const int CH = (NN + 255) / 256; // 196
  int base = t * CH;
  int s = 0;
  for (int i = 0; i < CH; ++i){ int idx = base + i; if (idx < NN) s += cnt[idx]; }
  lds[t] = s; __syncthreads();
  for (int off = 1; off < 256; off <<= 1){
    int v = (t >= off) ? lds[t - off] : 0;
    __syncthreads();
    lds[t] += v;
    __syncthreads();
  }
  int run = (t == 0) ? 0 : lds[t - 1];
  for (int i = 0; i < CH; ++i){
    int idx = base + i;
    if (idx < NN){ rp[idx] = run; run += cnt[idx]; }
  }
  if (t == 0) rp[NN] = lds[255];
}
__global__ void k_scatter(const int* src, const int* dst,
                          const int* rp, int* fill, int* perm){
  int e = blockIdx.x * 256 + threadIdx.x;
  if (e < NE){
    int d = dst[e];
    int pos = atomicAdd(&fill[d], 1);
    perm[rp[d] + pos] = src[e];
  }
}

// ---- mean aggregation: one 128-thread block per node ----
__global__ void k_agg(const unsigned short* hb, const int* rp, const int* perm,
                      const float* dinv, unsigned short* aggb){
  int n = blockIdx.x, c = threadIdx.x;
  int s = rp[n], e = rp[n + 1];
  float acc = 0.f;
  for (int i = s; i < e; ++i){
    int u = perm[i];
    acc += bf2f(hb[(size_t)u * DF + c]);
  }
  aggb[(size_t)n * DF + c] = f2bf(acc * dinv[n]);
}

// ---- layer GEMM via MFMA: hout = relu(h@Ws + agg@Wn + b) ----
// 64 rows x 128 cols per block; 4 waves x 16 rows; no LDS, B-frags from global.
__global__ __launch_bounds__(256) void k_layer_mfma(
    const unsigned short* hb, const unsigned short* aggb,
    const unsigned short* WsB, const unsigned short* WnB,
    const float* bias, unsigned short* hout){
  int t = threadIdx.x;
  int w = t >> 6, l = t & 63;
  int m = l & 15, q = l >> 4;
  int r0 = blockIdx.x * 64 + w * 16;
  int arow = r0 + m; if (arow > NN - 1) arow = NN - 1;
  const unsigned short* hp = hb   + (size_t)arow * DF + q * 8;
  const unsigned short* ap = aggb + (size_t)arow * DF + q * 8;
  f32x4 acc[8];
  for (int ct = 0; ct < 8; ++ct){
    float bbc = bias[ct * 16 + m];
    acc[ct] = (f32x4){bbc, bbc, bbc, bbc};
  }
  for (int kt = 0; kt < 4; ++kt){
    bf16x8 a_h = *(const bf16x8*)(hp + kt * 32);
    bf16x8 a_g = *(const bf16x8*)(ap + kt * 32);
    int kg = kt * 4 + q;
    for (int ct = 0; ct < 8; ++ct){
      bf16x8 b_s = *(const bf16x8*)(WsB + (((kg << 7) + ct * 16 + m) << 3));
      bf16x8 b_n = *(const bf16x8*)(WnB + (((kg << 7) + ct * 16 + m) << 3));
      acc[ct] = __builtin_amdgcn_mfma_f32_16x16x32_bf16(a_h, b_s, acc[ct], 0, 0, 0);
      acc[ct] = __builtin_amdgcn_mfma_f32_16x16x32_bf16(a_g, b_n, acc[ct], 0, 0, 0);
    }
  }
  for (int ct = 0; ct < 8; ++ct){
    int col = ct * 16 + m;
    for (int reg = 0; reg < 4; ++reg){
      int row = r0 + q * 4 + reg;
      if (row < NN) hout[(size_t)row * DF + col] = f2bf(fmaxf(acc[ct][reg], 0.f));
    }
  }
}

// ---- pair-feature GEMM via MFMA: z = [ha|hb||ha-hb|] @ W1 + b1 (fp32 out) ----
// 64 rows x 128 cols per block (256 blocks); F staged in LDS (row pad 392).
__global__ __launch_bounds__(256) void k_pair_mfma(
    const unsigned short* h2, const int* ia, const int* ib,
    const unsigned short* W1B, const float* b1, float* z){
  __shared__ __align__(16) unsigned short F[64 * 392];
  int t = threadIdx.x;
  int r0 = blockIdx.x * 64;
  // stage 64 rows: 4 threads per row, 32 k-positions each
  int i = t >> 2, qq = t & 3;
  int r = r0 + i;
  int a = ia[r], b = ib[r];
  const unsigned short* pa = h2 + (size_t)a * DF + qq * 32;
  const unsigned short* pb = h2 + (size_t)b * DF + qq * 32;
  unsigned short* fr = F + i * 392;
  for (int jj = 0; jj < 4; ++jj){
    bf16x8 va = *(const bf16x8*)(pa + jj * 8);
    bf16x8 vb = *(const bf16x8*)(pb + jj * 8);
    *(bf16x8*)(fr + qq * 32 + jj * 8) = va;
    *(bf16x8*)(fr + 128 + qq * 32 + jj * 8) = vb;
    unsigned short d[8];
    for (int e = 0; e < 8; ++e){
      float fa = bf2f((unsigned short)va[e]);
      float fb = bf2f((unsigned short)vb[e]);
      d[e] = f2bf(fabsf(fa - fb));
    }
    *(bf16x8*)(fr + 256 + qq * 32 + jj * 8) = *(bf16x8*)d;
  }
  __syncthreads();
  int w = t >> 6, l = t & 63;
  int m = l & 15, q = l >> 4;
  int rl = w * 16 + m;
  f32x4 acc[8];
  for (int ct = 0; ct < 8; ++ct){
    float bbc = b1[ct * 16 + m];
    acc[ct] = (f32x4){bbc, bbc, bbc, bbc};
  }
  for (int kt = 0; kt < 12; ++kt){
    bf16x8 af = *(const bf16x8*)(F + rl * 392 + kt * 32 + q * 8);
    int kg = kt * 4 + q;
    for (int ct = 0; ct < 8; ++ct){
      bf16x8 bfr = *(const bf16x8*)(W1B + (((kg << 7) + ct * 16 + m) << 3));
      acc[ct] = __builtin_amdgcn_mfma_f32_16x16x32_bf16(af, bfr, acc[ct], 0, 0, 0);
    }
  }
  for (int ct = 0; ct < 8; ++ct){
    int col = ct * 16 + m;
    int row = r0 + w * 16 + q * 4;
    z[(size_t)(row + 0) * DF + col] = acc[ct][0];
    z[(size_t)(row + 1) * DF + col] = acc[ct][1];
    z[(size_t)(row + 2) * DF + col] = acc[ct][2];
    z[(size_t)(row + 3) * DF + col] = acc[ct][3];
  }
}

// ---- per-column stats ----
__global__ void k_colstats(const float* z, float* ssum, float* ssq){
  int c = threadIdx.x; // 128
  const int RPB = NB / 256; // grid 256
  int r0 = blockIdx.x * RPB;
  float s = 0.f, s2 = 0.f;
  for (int r = r0; r < r0 + RPB; ++r){
    float v = z[(size_t)r * DF + c];
    s += v; s2 += v * v;
  }
  atomicAdd(&ssum[c], s);
  atomicAdd(&ssq[c], s2);
}
__global__ void k_finstats(const float* stats, float* mstd){
  int t = threadIdx.x; // 256
  int g = t >> 7, c = t & 127;
  float m = stats[g * 256 + c] / (float)NB;
  float v = stats[g * 256 + 128 + c] / (float)NB - m * m;
  mstd[g * 256 + c] = m;
  mstd[g * 256 + 128 + c] = 1.0f / sqrtf(v + 1e-5f);
}

// ---- normalize + relu, fp32 store into d_out ----
__global__ void k_norm(const float* z, const float* mstd,
                       const float* gamma, const float* beta, float* out){
  int i = blockIdx.x * 256 + threadIdx.x;
  if (i < NB * DF){
    int c = i & 127;
    float y = (z[i] - mstd[c]) * mstd[128 + c] * gamma[c] + beta[c];
    out[i] = fmaxf(y, 0.f);
  }
}

// ---- h_p = mmd @ W2 + b2, fp32 in/out ----
__global__ void k_hp(const float* mmd, const float* W2,
                     const float* b2, float* hp){
  __shared__ float s0[128], s1[128];
  int r = blockIdx.x, t = threadIdx.x;
  float x = mmd[(size_t)r * DF + t];
  s0[t] = x * W2[t * 2];
  s1[t] = x * W2[t * 2 + 1];
  __syncthreads();
  for (int off = 64; off > 0; off >>= 1){
    if (t < off){ s0[t] += s0[t + off]; s1[t] += s1[t + off]; }
    __syncthreads();
  }
  if (t == 0){
    hp[r * 2]     = s0[0] + b2[0];
    hp[r * 2 + 1] = s1[0] + b2[1];
  }
}

extern "C" __attribute__((used, visibility("default")))
void kernel_launch(void* const* d_in, const int* in_sizes, int n_in,
                   void* d_out, int out_size, void* d_ws, size_t ws_size,
                   hipStream_t stream){
  const float* h_in  = (const float*)d_in[0];
  const int* esrc = (const int*)d_in[1];
  const int* edst = (const int*)d_in[2];
  const int* x1   = (const int*)d_in[3];
  const int* x2   = (const int*)d_in[4];
  const int* x1t  = (const int*)d_in[5];
  const int* x2t  = (const int*)d_in[6];
  const float* Wself = (const float*)d_in[7];
  const float* Wneigh= (const float*)d_in[8];
  const float* bconv = (const float*)d_in[9];
  const float* W1    = (const float*)d_in[10];
  const float* b1    = (const float*)d_in[11];
  const float* gamma = (const float*)d_in[12];
  const float* beta  = (const float*)d_in[13];
  const float* W2    = (const float*)d_in[14];
  const float* b2    = (const float*)d_in[15];
  float* out = (float*)d_out;                   // fp32 outputs (proven R8/R9)
  float* hp_out   = out;                        // [NB,2]
  float* mmd_src  = out + 2 * NB;               // [NB,DF]
  float* mmd_tar  = mmd_src + (size_t)NB * DF;  // [NB,DF]

  // ---- workspace layout (~45.8 MB) ----
  float* zreg  = (float*)d_ws;                       // 2*NB*DF f32
  float* z_src = zreg;
  float* z_tar = zreg + (size_t)NB * DF;
  unsigned short* aggb = (unsigned short*)zreg;      // alias (dead before z)
  float* stats = zreg + (size_t)2 * NB * DF;         // 512
  float* mstd  = stats + 512;                        // 512
  float* dinv  = mstd + 512;                         // 50,048
  int* cnt  = (int*)(dinv + 50048);                  // 50,000
  int* fill = cnt + NN;                              // 50,000
  int* rp   = fill + NN;                             // 50,016
  int* perm = rp + 50016;                            // 600,000
  unsigned short* h_c = (unsigned short*)(perm + 600000); // NN*DF u16
  unsigned short* h1b = h_c + (size_t)NN * DF;            // NN*DF u16
  unsigned short* h2b = h_c;                 // alias: h_c dead after layer 0
  unsigned short* WsB = h1b + (size_t)NN * DF;  // 2*DF*DF u16 (both layers)
  unsigned short* WnB = WsB + 2 * DF * DF;      // 2*DF*DF u16
  unsigned short* W1B = WnB + 2 * DF * DF;      // 3*DF*DF u16

  // zero-init + weight swizzle + h cast
  k_zero_i<<<(2 * NN + 255) / 256, 256, 0, stream>>>(cnt, 2 * NN);
  k_zero_f<<<2, 256, 0, stream>>>(stats, 512);
  k_prep<<<192, 256, 0, stream>>>(Wself, Wneigh, W1, WsB, WnB, W1B);
  k_cvt_h<<<(NN * DF + 255) / 256, 256, 0, stream>>>(h_in, h_c, NN * DF);

  // CSR build
  k_hist<<<(NE + 255) / 256, 256, 0, stream>>>(edst, cnt);
  k_deginv<<<(NN + 255) / 256, 256, 0, stream>>>(cnt, dinv);
  k_scan<<<1, 256, 0, stream>>>(cnt, rp);
  k_scatter<<<(NE + 255) / 256, 256, 0, stream>>>(esrc, edst, rp, fill, perm);

  // SAGE layer 0: h_c -> h1b
  k_agg<<<NN, 128, 0, stream>>>(h_c, rp, perm, dinv, aggb);
  k_layer_mfma<<<(NN + 63) / 64, 256, 0, stream>>>(h_c, aggb, WsB, WnB, bconv, h1b);
  // SAGE layer 1: h1b -> h2b
  k_agg<<<NN, 128, 0, stream>>>(h1b, rp, perm, dinv, aggb);
  k_layer_mfma<<<(NN + 63) / 64, 256, 0, stream>>>(h1b, aggb, WsB + DF * DF,
                                                   WnB + DF * DF, bconv + DF, h2b);

  // head
  k_pair_mfma<<<NB / 64, 256, 0, stream>>>(h2b, x1, x2, W1B, b1, z_src);
  k_pair_mfma<<<NB / 64, 256, 0, stream>>>(h2b, x1t, x2t, W1B, b1, z_tar);
  k_colstats<<<256, 128, 0, stream>>>(z_src, stats, stats + 128);
  k_colstats<<<256, 128, 0, stream>>>(z_tar, stats + 256, stats + 384);
  k_finstats<<<1, 256, 0, stream>>>(stats, mstd);
  k_norm<<<(NB * DF + 255) / 256, 256, 0, stream>>>(z_src, mstd, gamma, beta, mmd_src);
  k_norm<<<(NB * DF + 255) / 256, 256, 0, stream>>>(z_tar, mstd + 256, gamma, beta, mmd_tar);
  k_hp<<<NB, 128, 0, stream>>>(mmd_src, W2, b2, hp_out);
}

// Round 11
// 392.900 us; speedup vs baseline: 2.3346x; 1.2721x over previous
//
#include <hip/hip_runtime.h>

#define NN 50000   // nodes
#define NE 600000  // edges
#define DF 128     // features
#define NB 16384   // pair batch

typedef short bf16x8 __attribute__((ext_vector_type(8)));
typedef float f32x4 __attribute__((ext_vector_type(4)));

__device__ __forceinline__ float bf2f(unsigned short u){
  return __uint_as_float(((unsigned int)u) << 16);
}
__device__ __forceinline__ unsigned short f2bf(float x){
  unsigned int b = __float_as_uint(x);
  return (unsigned short)((b + 0x7FFFu + ((b >> 16) & 1u)) >> 16);
}

// Original template symbol (defined, never launched).
__global__ void GraphSAGE_8504035246140_kernel(){ }

// ---- zero-init ----
__global__ void k_zero_i(int* p, int n){
  int i = blockIdx.x * 256 + threadIdx.x;
  if (i < n) p[i] = 0;
}
__global__ void k_zero_f(float* p, int n){
  int i = blockIdx.x * 256 + threadIdx.x;
  if (i < n) p[i] = 0.f;
}

// ---- h (fp32) -> bf16, 8 elems/thread ----
__global__ void k_cvt_h(const float* src, unsigned short* dst, int n8){
  int i = blockIdx.x * 256 + threadIdx.x;
  if (i < n8){
    const float4* s = (const float4*)src;
    float4 v0 = s[i * 2], v1 = s[i * 2 + 1];
    unsigned short d[8] = {f2bf(v0.x), f2bf(v0.y), f2bf(v0.z), f2bf(v0.w),
                           f2bf(v1.x), f2bf(v1.y), f2bf(v1.z), f2bf(v1.w)};
    *(bf16x8*)(dst + i * 8) = *(bf16x8*)d;
  }
}

// ---- weight swizzle into MFMA B-fragment order: B[k][n] -> [k>>3][n][k&7] ----
__global__ void k_prep(const float* Ws, const float* Wn, const float* W1,
                       unsigned short* WsB, unsigned short* WnB, unsigned short* W1B){
  int idx = blockIdx.x * 256 + threadIdx.x;   // grid 192*256 = 49152
  if (idx < 2 * DF * DF){
    int layer = idx >> 14;
    int e = idx & (DF * DF - 1);
    int k = e >> 7, n = e & 127;
    int dst = layer * DF * DF + (((k >> 3) * 128 + n) << 3) + (k & 7);
    WsB[dst] = f2bf(Ws[idx]);
    WnB[dst] = f2bf(Wn[idx]);
  }
  if (idx < 3 * DF * DF){
    int k = idx >> 7, n = idx & 127;          // W1: 384x128
    W1B[(((k >> 3) * 128 + n) << 3) + (k & 7)] = f2bf(W1[idx]);
  }
}

// ---- CSR build ----
__global__ void k_hist(const int* dst, int* cnt){
  int e = blockIdx.x * 256 + threadIdx.x;
  if (e < NE) atomicAdd(&cnt[dst[e]], 1);
}

// ---- 3-phase multi-block scan ----
__global__ void k_scan1(const int* cnt, int* bsum){   // grid 196
  __shared__ int l[256];
  int t = threadIdx.x, i = blockIdx.x * 256 + t;
  l[t] = (i < NN) ? cnt[i] : 0;
  __syncthreads();
  for (int o = 128; o > 0; o >>= 1){
    if (t < o) l[t] += l[t + o];
    __syncthreads();
  }
  if (t == 0) bsum[blockIdx.x] = l[0];
}
__global__ void k_scan2(int* bsum){                   // 1 block, inclusive in-place
  __shared__ int l[256];
  int t = threadIdx.x;
  l[t] = (t < 196) ? bsum[t] : 0;
  __syncthreads();
  for (int o = 1; o < 256; o <<= 1){
    int v = (t >= o) ? l[t - o] : 0;
    __syncthreads();
    l[t] += v;
    __syncthreads();
  }
  bsum[t] = l[t];
}
__global__ void k_scan3(const int* cnt, const int* bsum, int* rp, float* dinv){ // grid 196
  __shared__ int l[256];
  int t = threadIdx.x, i = blockIdx.x * 256 + t;
  int v = (i < NN) ? cnt[i] : 0;
  l[t] = v;
  __syncthreads();
  for (int o = 1; o < 256; o <<= 1){
    int x = (t >= o) ? l[t - o] : 0;
    __syncthreads();
    l[t] += x;
    __syncthreads();
  }
  int base = (blockIdx.x == 0) ? 0 : bsum[blockIdx.x - 1];
  if (i < NN){
    rp[i] = base + l[t] - v;                 // exclusive
    dinv[i] = 1.0f / fmaxf((float)v, 1.0f);  // fused deginv
    if (i == NN - 1) rp[NN] = base + l[t];
  }
}

__global__ void k_scatter(const int* src, const int* dst,
                          const int* rp, int* fill, int* perm){
  int e = blockIdx.x * 256 + threadIdx.x;
  if (e < NE){
    int d = dst[e];
    int pos = atomicAdd(&fill[d], 1);
    perm[rp[d] + pos] = src[e];
  }
}

// ---- mean aggregation: one wave per node, u32 (2 bf16) per lane ----
__global__ __launch_bounds__(256) void k_agg(
    const unsigned int* hb32, const int* rp, const int* perm,
    const float* dinv, unsigned int* agg32){
  int n = blockIdx.x * 4 + (threadIdx.x >> 6);
  if (n >= NN) return;
  int l = threadIdx.x & 63;
  int s = rp[n], e = rp[n + 1];
  float a0 = 0.f, a1 = 0.f;
  for (int i = s; i < e; ++i){
    unsigned int u = hb32[(size_t)perm[i] * 64 + l];
    a0 += __uint_as_float(u << 16);
    a1 += __uint_as_float(u & 0xffff0000u);
  }
  float di = dinv[n];
  agg32[(size_t)n * 64 + l] =
      (unsigned int)f2bf(a0 * di) | ((unsigned int)f2bf(a1 * di) << 16);
}

// ---- layer GEMM via MFMA: hout = relu(h@Ws + agg@Wn + b) ----
__global__ __launch_bounds__(256) void k_layer_mfma(
    const unsigned short* hb, const unsigned short* aggb,
    const unsigned short* WsB, const unsigned short* WnB,
    const float* bias, unsigned short* hout){
  int t = threadIdx.x;
  int w = t >> 6, l = t & 63;
  int m = l & 15, q = l >> 4;
  int r0 = blockIdx.x * 64 + w * 16;
  int arow = r0 + m; if (arow > NN - 1) arow = NN - 1;
  const unsigned short* hp = hb   + (size_t)arow * DF + q * 8;
  const unsigned short* ap = aggb + (size_t)arow * DF + q * 8;
  f32x4 acc[8];
  for (int ct = 0; ct < 8; ++ct){
    float bbc = bias[ct * 16 + m];
    acc[ct] = (f32x4){bbc, bbc, bbc, bbc};
  }
  for (int kt = 0; kt < 4; ++kt){
    bf16x8 a_h = *(const bf16x8*)(hp + kt * 32);
    bf16x8 a_g = *(const bf16x8*)(ap + kt * 32);
    int kg = kt * 4 + q;
    for (int ct = 0; ct < 8; ++ct){
      bf16x8 b_s = *(const bf16x8*)(WsB + (((kg << 7) + ct * 16 + m) << 3));
      bf16x8 b_n = *(const bf16x8*)(WnB + (((kg << 7) + ct * 16 + m) << 3));
      acc[ct] = __builtin_amdgcn_mfma_f32_16x16x32_bf16(a_h, b_s, acc[ct], 0, 0, 0);
      acc[ct] = __builtin_amdgcn_mfma_f32_16x16x32_bf16(a_g, b_n, acc[ct], 0, 0, 0);
    }
  }
  for (int ct = 0; ct < 8; ++ct){
    int col = ct * 16 + m;
    for (int reg = 0; reg < 4; ++reg){
      int row = r0 + q * 4 + reg;
      if (row < NN) hout[(size_t)row * DF + col] = f2bf(fmaxf(acc[ct][reg], 0.f));
    }
  }
}

// ---- pair-feature GEMM via MFMA: z = [ha|hb||ha-hb|] @ W1 + b1 (fp32 out) ----
__global__ __launch_bounds__(256) void k_pair_mfma(
    const unsigned short* h2, const int* ia, const int* ib,
    const unsigned short* W1B, const float* b1, float* z){
  __shared__ __align__(16) unsigned short F[64 * 392];
  int t = threadIdx.x;
  int r0 = blockIdx.x * 64;
  int i = t >> 2, qq = t & 3;
  int r = r0 + i;
  int a = ia[r], b = ib[r];
  const unsigned short* pa = h2 + (size_t)a * DF + qq * 32;
  const unsigned short* pb = h2 + (size_t)b * DF + qq * 32;
  unsigned short* fr = F + i * 392;
  for (int jj = 0; jj < 4; ++jj){
    bf16x8 va = *(const bf16x8*)(pa + jj * 8);
    bf16x8 vb = *(const bf16x8*)(pb + jj * 8);
    *(bf16x8*)(fr + qq * 32 + jj * 8) = va;
    *(bf16x8*)(fr + 128 + qq * 32 + jj * 8) = vb;
    unsigned short d[8];
    for (int e = 0; e < 8; ++e){
      float fa = bf2f((unsigned short)va[e]);
      float fb = bf2f((unsigned short)vb[e]);
      d[e] = f2bf(fabsf(fa - fb));
    }
    *(bf16x8*)(fr + 256 + qq * 32 + jj * 8) = *(bf16x8*)d;
  }
  __syncthreads();
  int w = t >> 6, l = t & 63;
  int m = l & 15, q = l >> 4;
  int rl = w * 16 + m;
  f32x4 acc[8];
  for (int ct = 0; ct < 8; ++ct){
    float bbc = b1[ct * 16 + m];
    acc[ct] = (f32x4){bbc, bbc, bbc, bbc};
  }
  for (int kt = 0; kt < 12; ++kt){
    bf16x8 af = *(const bf16x8*)(F + rl * 392 + kt * 32 + q * 8);
    int kg = kt * 4 + q;
    for (int ct = 0; ct < 8; ++ct){
      bf16x8 bfr = *(const bf16x8*)(W1B + (((kg << 7) + ct * 16 + m) << 3));
      acc[ct] = __builtin_amdgcn_mfma_f32_16x16x32_bf16(af, bfr, acc[ct], 0, 0, 0);
    }
  }
  for (int ct = 0; ct < 8; ++ct){
    int col = ct * 16 + m;
    int row = r0 + w * 16 + q * 4;
    z[(size_t)(row + 0) * DF + col] = acc[ct][0];
    z[(size_t)(row + 1) * DF + col] = acc[ct][1];
    z[(size_t)(row + 2) * DF + col] = acc[ct][2];
    z[(size_t)(row + 3) * DF + col] = acc[ct][3];
  }
}

// ---- per-column stats ----
__global__ void k_colstats(const float* z, float* ssum, float* ssq){
  int c = threadIdx.x; // 128
  const int RPB = NB / 256; // grid 256
  int r0 = blockIdx.x * RPB;
  float s = 0.f, s2 = 0.f;
  for (int r = r0; r < r0 + RPB; ++r){
    float v = z[(size_t)r * DF + c];
    s += v; s2 += v * v;
  }
  atomicAdd(&ssum[c], s);
  atomicAdd(&ssq[c], s2);
}
__global__ void k_finstats(const float* stats, float* mstd){
  int t = threadIdx.x; // 256
  int g = t >> 7, c = t & 127;
  float m = stats[g * 256 + c] / (float)NB;
  float v = stats[g * 256 + 128 + c] / (float)NB - m * m;
  mstd[g * 256 + c] = m;
  mstd[g * 256 + 128 + c] = 1.0f / sqrtf(v + 1e-5f);
}

// ---- normalize + relu, fp32 store into d_out ----
__global__ void k_norm(const float* z, const float* mstd,
                       const float* gamma, const float* beta, float* out){
  int i = blockIdx.x * 256 + threadIdx.x;
  if (i < NB * DF){
    int c = i & 127;
    float y = (z[i] - mstd[c]) * mstd[128 + c] * gamma[c] + beta[c];
    out[i] = fmaxf(y, 0.f);
  }
}

// ---- h_p = mmd @ W2 + b2, fp32 in/out ----
__global__ void k_hp(const float* mmd, const float* W2,
                     const float* b2, float* hp){
  __shared__ float s0[128], s1[128];
  int r = blockIdx.x, t = threadIdx.x;
  float x = mmd[(size_t)r * DF + t];
  s0[t] = x * W2[t * 2];
  s1[t] = x * W2[t * 2 + 1];
  __syncthreads();
  for (int off = 64; off > 0; off >>= 1){
    if (t < off){ s0[t] += s0[t + off]; s1[t] += s1[t + off]; }
    __syncthreads();
  }
  if (t == 0){
    hp[r * 2]     = s0[0] + b2[0];
    hp[r * 2 + 1] = s1[0] + b2[1];
  }
}

extern "C" __attribute__((used, visibility("default")))
void kernel_launch(void* const* d_in, const int* in_sizes, int n_in,
                   void* d_out, int out_size, void* d_ws, size_t ws_size,
                   hipStream_t stream){
  const float* h_in  = (const float*)d_in[0];
  const int* esrc = (const int*)d_in[1];
  const int* edst = (const int*)d_in[2];
  const int* x1   = (const int*)d_in[3];
  const int* x2   = (const int*)d_in[4];
  const int* x1t  = (const int*)d_in[5];
  const int* x2t  = (const int*)d_in[6];
  const float* Wself = (const float*)d_in[7];
  const float* Wneigh= (const float*)d_in[8];
  const float* bconv = (const float*)d_in[9];
  const float* W1    = (const float*)d_in[10];
  const float* b1    = (const float*)d_in[11];
  const float* gamma = (const float*)d_in[12];
  const float* beta  = (const float*)d_in[13];
  const float* W2    = (const float*)d_in[14];
  const float* b2    = (const float*)d_in[15];
  float* out = (float*)d_out;                   // fp32 outputs
  float* hp_out   = out;                        // [NB,2]
  float* mmd_src  = out + 2 * NB;               // [NB,DF]
  float* mmd_tar  = mmd_src + (size_t)NB * DF;  // [NB,DF]

  // ---- workspace layout (~45.8 MB) ----
  float* zreg  = (float*)d_ws;                       // 2*NB*DF f32
  float* z_src = zreg;
  float* z_tar = zreg + (size_t)NB * DF;
  unsigned short* aggb = (unsigned short*)zreg;      // alias (dead before z)
  float* stats = zreg + (size_t)2 * NB * DF;         // 512
  float* mstd  = stats + 512;                        // 512
  float* dinv  = mstd + 512;                         // 50,048
  int* cnt  = (int*)(dinv + 50048);                  // 50,000
  int* fill = cnt + NN;                              // 50,000
  int* rp   = fill + NN;                             // 50,016
  int* perm = rp + 50016;                            // 600,000
  int* bsum = perm + 600000;                         // 256
  unsigned short* h_c = (unsigned short*)(bsum + 256);    // NN*DF u16
  unsigned short* h1b = h_c + (size_t)NN * DF;            // NN*DF u16
  unsigned short* h2b = h_c;                 // alias: h_c dead after layer 0
  unsigned short* WsB = h1b + (size_t)NN * DF;  // 2*DF*DF u16 (both layers)
  unsigned short* WnB = WsB + 2 * DF * DF;      // 2*DF*DF u16
  unsigned short* W1B = WnB + 2 * DF * DF;      // 3*DF*DF u16

  // zero-init + weight swizzle + h cast
  k_zero_i<<<(2 * NN + 255) / 256, 256, 0, stream>>>(cnt, 2 * NN);
  k_zero_f<<<2, 256, 0, stream>>>(stats, 512);
  k_prep<<<192, 256, 0, stream>>>(Wself, Wneigh, W1, WsB, WnB, W1B);
  k_cvt_h<<<(NN * DF / 8 + 255) / 256, 256, 0, stream>>>(h_in, h_c, NN * DF / 8);

  // CSR build (multi-block scan, deginv fused into scan3)
  k_hist<<<(NE + 255) / 256, 256, 0, stream>>>(edst, cnt);
  k_scan1<<<196, 256, 0, stream>>>(cnt, bsum);
  k_scan2<<<1, 256, 0, stream>>>(bsum);
  k_scan3<<<196, 256, 0, stream>>>(cnt, bsum, rp, dinv);
  k_scatter<<<(NE + 255) / 256, 256, 0, stream>>>(esrc, edst, rp, fill, perm);

  // SAGE layer 0: h_c -> h1b
  k_agg<<<(NN + 3) / 4, 256, 0, stream>>>((const unsigned int*)h_c, rp, perm,
                                          dinv, (unsigned int*)aggb);
  k_layer_mfma<<<(NN + 63) / 64, 256, 0, stream>>>(h_c, aggb, WsB, WnB, bconv, h1b);
  // SAGE layer 1: h1b -> h2b
  k_agg<<<(NN + 3) / 4, 256, 0, stream>>>((const unsigned int*)h1b, rp, perm,
                                          dinv, (unsigned int*)aggb);
  k_layer_mfma<<<(NN + 63) / 64, 256, 0, stream>>>(h1b, aggb, WsB + DF * DF,
                                                   WnB + DF * DF, bconv + DF, h2b);

  // head
  k_pair_mfma<<<NB / 64, 256, 0, stream>>>(h2b, x1, x2, W1B, b1, z_src);
  k_pair_mfma<<<NB / 64, 256, 0, stream>>>(h2b, x1t, x2t, W1B, b1, z_tar);
  k_colstats<<<256, 128, 0, stream>>>(z_src, stats, stats + 128);
  k_colstats<<<256, 128, 0, stream>>>(z_tar, stats + 256, stats + 384);
  k_finstats<<<1, 256, 0, stream>>>(stats, mstd);
  k_norm<<<(NB * DF + 255) / 256, 256, 0, stream>>>(z_src, mstd, gamma, beta, mmd_src);
  k_norm<<<(NB * DF + 255) / 256, 256, 0, stream>>>(z_tar, mstd + 256, gamma, beta, mmd_tar);
  k_hp<<<NB, 128, 0, stream>>>(mmd_src, W2, b2, hp_out);
}

// Round 12
// 331.531 us; speedup vs baseline: 2.7667x; 1.1851x over previous
//
#include <hip/hip_runtime.h>

#define NN 50000   // nodes
#define NE 600000  // edges
#define DF 128     // features
#define NB 16384   // pair batch

typedef short bf16x8 __attribute__((ext_vector_type(8)));
typedef float f32x4 __attribute__((ext_vector_type(4)));

__device__ __forceinline__ float bf2f(unsigned short u){
  return __uint_as_float(((unsigned int)u) << 16);
}
__device__ __forceinline__ unsigned short f2bf(float x){
  unsigned int b = __float_as_uint(x);
  return (unsigned short)((b + 0x7FFFu + ((b >> 16) & 1u)) >> 16);
}

// Original template symbol (defined, never launched).
__global__ void GraphSAGE_8504035246140_kernel(){ }

// ---- zero-init ----
__global__ void k_zero_i(int* p, int n){
  int i = blockIdx.x * 256 + threadIdx.x;
  if (i < n) p[i] = 0;
}
__global__ void k_zero_f(float* p, int n){
  int i = blockIdx.x * 256 + threadIdx.x;
  if (i < n) p[i] = 0.f;
}

// ---- h (fp32) -> bf16, 8 elems/thread ----
__global__ void k_cvt_h(const float* src, unsigned short* dst, int n8){
  int i = blockIdx.x * 256 + threadIdx.x;
  if (i < n8){
    const float4* s = (const float4*)src;
    float4 v0 = s[i * 2], v1 = s[i * 2 + 1];
    unsigned short d[8] = {f2bf(v0.x), f2bf(v0.y), f2bf(v0.z), f2bf(v0.w),
                           f2bf(v1.x), f2bf(v1.y), f2bf(v1.z), f2bf(v1.w)};
    *(bf16x8*)(dst + i * 8) = *(bf16x8*)d;
  }
}

// ---- weight swizzle into MFMA B-fragment order: B[k][n] -> [k>>3][n][k&7] ----
__global__ void k_prep(const float* Ws, const float* Wn, const float* W1,
                       unsigned short* WsB, unsigned short* WnB, unsigned short* W1B){
  int idx = blockIdx.x * 256 + threadIdx.x;   // grid 192*256 = 49152
  if (idx < 2 * DF * DF){
    int layer = idx >> 14;
    int e = idx & (DF * DF - 1);
    int k = e >> 7, n = e & 127;
    int dst = layer * DF * DF + (((k >> 3) * 128 + n) << 3) + (k & 7);
    WsB[dst] = f2bf(Ws[idx]);
    WnB[dst] = f2bf(Wn[idx]);
  }
  if (idx < 3 * DF * DF){
    int k = idx >> 7, n = idx & 127;          // W1: 384x128
    W1B[(((k >> 3) * 128 + n) << 3) + (k & 7)] = f2bf(W1[idx]);
  }
}

// ---- CSR build ----
__global__ void k_hist(const int* dst, int* cnt){
  int e = blockIdx.x * 256 + threadIdx.x;
  if (e < NE) atomicAdd(&cnt[dst[e]], 1);
}

// ---- 3-phase multi-block scan ----
__global__ void k_scan1(const int* cnt, int* bsum){   // grid 196
  __shared__ int l[256];
  int t = threadIdx.x, i = blockIdx.x * 256 + t;
  l[t] = (i < NN) ? cnt[i] : 0;
  __syncthreads();
  for (int o = 128; o > 0; o >>= 1){
    if (t < o) l[t] += l[t + o];
    __syncthreads();
  }
  if (t == 0) bsum[blockIdx.x] = l[0];
}
__global__ void k_scan2(int* bsum){                   // 1 block, inclusive in-place
  __shared__ int l[256];
  int t = threadIdx.x;
  l[t] = (t < 196) ? bsum[t] : 0;
  __syncthreads();
  for (int o = 1; o < 256; o <<= 1){
    int v = (t >= o) ? l[t - o] : 0;
    __syncthreads();
    l[t] += v;
    __syncthreads();
  }
  bsum[t] = l[t];
}
__global__ void k_scan3(const int* cnt, const int* bsum, int* rp, float* dinv){ // grid 196
  __shared__ int l[256];
  int t = threadIdx.x, i = blockIdx.x * 256 + t;
  int v = (i < NN) ? cnt[i] : 0;
  l[t] = v;
  __syncthreads();
  for (int o = 1; o < 256; o <<= 1){
    int x = (t >= o) ? l[t - o] : 0;
    __syncthreads();
    l[t] += x;
    __syncthreads();
  }
  int base = (blockIdx.x == 0) ? 0 : bsum[blockIdx.x - 1];
  if (i < NN){
    rp[i] = base + l[t] - v;                 // exclusive
    dinv[i] = 1.0f / fmaxf((float)v, 1.0f);  // fused deginv
    if (i == NN - 1) rp[NN] = base + l[t];
  }
}

__global__ void k_scatter(const int* src, const int* dst,
                          const int* rp, int* fill, int* perm){
  int e = blockIdx.x * 256 + threadIdx.x;
  if (e < NE){
    int d = dst[e];
    int pos = atomicAdd(&fill[d], 1);
    perm[rp[d] + pos] = src[e];
  }
}

// ---- mean aggregation: one wave per node, 8-way unrolled edge loop ----
// u32 = 2 bf16 per lane; 8 independent row loads in flight per wave.
__global__ __launch_bounds__(256) void k_agg(
    const unsigned int* hb32, const int* rp, const int* perm,
    const float* dinv, unsigned int* agg32){
  int n = blockIdx.x * 4 + (threadIdx.x >> 6);
  if (n >= NN) return;
  int l = threadIdx.x & 63;
  int s = rp[n], e = rp[n + 1];
  float a0 = 0.f, a1 = 0.f, b0 = 0.f, b1 = 0.f;
  int i = s;
  for (; i + 8 <= e; i += 8){
    int u0 = perm[i],     u1 = perm[i + 1], u2 = perm[i + 2], u3 = perm[i + 3];
    int u4 = perm[i + 4], u5 = perm[i + 5], u6 = perm[i + 6], u7 = perm[i + 7];
    unsigned int x0 = hb32[(size_t)u0 * 64 + l];
    unsigned int x1 = hb32[(size_t)u1 * 64 + l];
    unsigned int x2 = hb32[(size_t)u2 * 64 + l];
    unsigned int x3 = hb32[(size_t)u3 * 64 + l];
    unsigned int x4 = hb32[(size_t)u4 * 64 + l];
    unsigned int x5 = hb32[(size_t)u5 * 64 + l];
    unsigned int x6 = hb32[(size_t)u6 * 64 + l];
    unsigned int x7 = hb32[(size_t)u7 * 64 + l];
    a0 += __uint_as_float(x0 << 16); a1 += __uint_as_float(x0 & 0xffff0000u);
    b0 += __uint_as_float(x1 << 16); b1 += __uint_as_float(x1 & 0xffff0000u);
    a0 += __uint_as_float(x2 << 16); a1 += __uint_as_float(x2 & 0xffff0000u);
    b0 += __uint_as_float(x3 << 16); b1 += __uint_as_float(x3 & 0xffff0000u);
    a0 += __uint_as_float(x4 << 16); a1 += __uint_as_float(x4 & 0xffff0000u);
    b0 += __uint_as_float(x5 << 16); b1 += __uint_as_float(x5 & 0xffff0000u);
    a0 += __uint_as_float(x6 << 16); a1 += __uint_as_float(x6 & 0xffff0000u);
    b0 += __uint_as_float(x7 << 16); b1 += __uint_as_float(x7 & 0xffff0000u);
  }
  for (; i < e; ++i){
    unsigned int u = hb32[(size_t)perm[i] * 64 + l];
    a0 += __uint_as_float(u << 16);
    a1 += __uint_as_float(u & 0xffff0000u);
  }
  a0 += b0; a1 += b1;
  float di = dinv[n];
  agg32[(size_t)n * 64 + l] =
      (unsigned int)f2bf(a0 * di) | ((unsigned int)f2bf(a1 * di) << 16);
}

// ---- layer GEMM via MFMA: hout = relu(h@Ws + agg@Wn + b) ----
__global__ __launch_bounds__(256) void k_layer_mfma(
    const unsigned short* hb, const unsigned short* aggb,
    const unsigned short* WsB, const unsigned short* WnB,
    const float* bias, unsigned short* hout){
  int t = threadIdx.x;
  int w = t >> 6, l = t & 63;
  int m = l & 15, q = l >> 4;
  int r0 = blockIdx.x * 64 + w * 16;
  int arow = r0 + m; if (arow > NN - 1) arow = NN - 1;
  const unsigned short* hp = hb   + (size_t)arow * DF + q * 8;
  const unsigned short* ap = aggb + (size_t)arow * DF + q * 8;
  f32x4 acc[8];
  for (int ct = 0; ct < 8; ++ct){
    float bbc = bias[ct * 16 + m];
    acc[ct] = (f32x4){bbc, bbc, bbc, bbc};
  }
  for (int kt = 0; kt < 4; ++kt){
    bf16x8 a_h = *(const bf16x8*)(hp + kt * 32);
    bf16x8 a_g = *(const bf16x8*)(ap + kt * 32);
    int kg = kt * 4 + q;
    for (int ct = 0; ct < 8; ++ct){
      bf16x8 b_s = *(const bf16x8*)(WsB + (((kg << 7) + ct * 16 + m) << 3));
      bf16x8 b_n = *(const bf16x8*)(WnB + (((kg << 7) + ct * 16 + m) << 3));
      acc[ct] = __builtin_amdgcn_mfma_f32_16x16x32_bf16(a_h, b_s, acc[ct], 0, 0, 0);
      acc[ct] = __builtin_amdgcn_mfma_f32_16x16x32_bf16(a_g, b_n, acc[ct], 0, 0, 0);
    }
  }
  for (int ct = 0; ct < 8; ++ct){
    int col = ct * 16 + m;
    for (int reg = 0; reg < 4; ++reg){
      int row = r0 + q * 4 + reg;
      if (row < NN) hout[(size_t)row * DF + col] = f2bf(fmaxf(acc[ct][reg], 0.f));
    }
  }
}

// ---- pair-feature GEMM via MFMA: z = [ha|hb||ha-hb|] @ W1 + b1 (fp32 out) ----
__global__ __launch_bounds__(256) void k_pair_mfma(
    const unsigned short* h2, const int* ia, const int* ib,
    const unsigned short* W1B, const float* b1, float* z){
  __shared__ __align__(16) unsigned short F[64 * 392];
  int t = threadIdx.x;
  int r0 = blockIdx.x * 64;
  int i = t >> 2, qq = t & 3;
  int r = r0 + i;
  int a = ia[r], b = ib[r];
  const unsigned short* pa = h2 + (size_t)a * DF + qq * 32;
  const unsigned short* pb = h2 + (size_t)b * DF + qq * 32;
  unsigned short* fr = F + i * 392;
  for (int jj = 0; jj < 4; ++jj){
    bf16x8 va = *(const bf16x8*)(pa + jj * 8);
    bf16x8 vb = *(const bf16x8*)(pb + jj * 8);
    *(bf16x8*)(fr + qq * 32 + jj * 8) = va;
    *(bf16x8*)(fr + 128 + qq * 32 + jj * 8) = vb;
    unsigned short d[8];
    for (int e = 0; e < 8; ++e){
      float fa = bf2f((unsigned short)va[e]);
      float fb = bf2f((unsigned short)vb[e]);
      d[e] = f2bf(fabsf(fa - fb));
    }
    *(bf16x8*)(fr + 256 + qq * 32 + jj * 8) = *(bf16x8*)d;
  }
  __syncthreads();
  int w = t >> 6, l = t & 63;
  int m = l & 15, q = l >> 4;
  int rl = w * 16 + m;
  f32x4 acc[8];
  for (int ct = 0; ct < 8; ++ct){
    float bbc = b1[ct * 16 + m];
    acc[ct] = (f32x4){bbc, bbc, bbc, bbc};
  }
  for (int kt = 0; kt < 12; ++kt){
    bf16x8 af = *(const bf16x8*)(F + rl * 392 + kt * 32 + q * 8);
    int kg = kt * 4 + q;
    for (int ct = 0; ct < 8; ++ct){
      bf16x8 bfr = *(const bf16x8*)(W1B + (((kg << 7) + ct * 16 + m) << 3));
      acc[ct] = __builtin_amdgcn_mfma_f32_16x16x32_bf16(af, bfr, acc[ct], 0, 0, 0);
    }
  }
  for (int ct = 0; ct < 8; ++ct){
    int col = ct * 16 + m;
    int row = r0 + w * 16 + q * 4;
    z[(size_t)(row + 0) * DF + col] = acc[ct][0];
    z[(size_t)(row + 1) * DF + col] = acc[ct][1];
    z[(size_t)(row + 2) * DF + col] = acc[ct][2];
    z[(size_t)(row + 3) * DF + col] = acc[ct][3];
  }
}

// ---- per-column stats, both batches via blockIdx.y ----
__global__ void k_colstats(const float* zbase, float* stats){
  int c = threadIdx.x; // 128
  int g = blockIdx.y;  // 0 = src, 1 = tar
  const float* z = zbase + (size_t)g * NB * DF;
  const int RPB = NB / 256; // grid.x 256
  int r0 = blockIdx.x * RPB;
  float s = 0.f, s2 = 0.f;
  for (int r = r0; r < r0 + RPB; ++r){
    float v = z[(size_t)r * DF + c];
    s += v; s2 += v * v;
  }
  atomicAdd(&stats[g * 256 + c], s);
  atomicAdd(&stats[g * 256 + 128 + c], s2);
}
__global__ void k_finstats(const float* stats, float* mstd){
  int t = threadIdx.x; // 256
  int g = t >> 7, c = t & 127;
  float m = stats[g * 256 + c] / (float)NB;
  float v = stats[g * 256 + 128 + c] / (float)NB - m * m;
  mstd[g * 256 + c] = m;
  mstd[g * 256 + 128 + c] = 1.0f / sqrtf(v + 1e-5f);
}

// ---- normalize + relu, both batches via blockIdx.y, fp32 store ----
__global__ void k_norm(const float* zbase, const float* mstd,
                       const float* gamma, const float* beta, float* outbase){
  int g = blockIdx.y;
  int i = blockIdx.x * 256 + threadIdx.x;
  if (i < NB * DF){
    int c = i & 127;
    const float* z = zbase + (size_t)g * NB * DF;
    float* o = outbase + (size_t)g * NB * DF;
    float y = (z[i] - mstd[g * 256 + c]) * mstd[g * 256 + 128 + c] * gamma[c] + beta[c];
    o[i] = fmaxf(y, 0.f);
  }
}

// ---- h_p = mmd @ W2 + b2, fp32 in/out ----
__global__ void k_hp(const float* mmd, const float* W2,
                     const float* b2, float* hp){
  __shared__ float s0[128], s1[128];
  int r = blockIdx.x, t = threadIdx.x;
  float x = mmd[(size_t)r * DF + t];
  s0[t] = x * W2[t * 2];
  s1[t] = x * W2[t * 2 + 1];
  __syncthreads();
  for (int off = 64; off > 0; off >>= 1){
    if (t < off){ s0[t] += s0[t + off]; s1[t] += s1[t + off]; }
    __syncthreads();
  }
  if (t == 0){
    hp[r * 2]     = s0[0] + b2[0];
    hp[r * 2 + 1] = s1[0] + b2[1];
  }
}

extern "C" __attribute__((used, visibility("default")))
void kernel_launch(void* const* d_in, const int* in_sizes, int n_in,
                   void* d_out, int out_size, void* d_ws, size_t ws_size,
                   hipStream_t stream){
  const float* h_in  = (const float*)d_in[0];
  const int* esrc = (const int*)d_in[1];
  const int* edst = (const int*)d_in[2];
  const int* x1   = (const int*)d_in[3];
  const int* x2   = (const int*)d_in[4];
  const int* x1t  = (const int*)d_in[5];
  const int* x2t  = (const int*)d_in[6];
  const float* Wself = (const float*)d_in[7];
  const float* Wneigh= (const float*)d_in[8];
  const float* bconv = (const float*)d_in[9];
  const float* W1    = (const float*)d_in[10];
  const float* b1    = (const float*)d_in[11];
  const float* gamma = (const float*)d_in[12];
  const float* beta  = (const float*)d_in[13];
  const float* W2    = (const float*)d_in[14];
  const float* b2    = (const float*)d_in[15];
  float* out = (float*)d_out;                   // fp32 outputs
  float* hp_out   = out;                        // [NB,2]
  float* mmd_src  = out + 2 * NB;               // [NB,DF] (tar follows contiguously)

  // ---- workspace layout (~45.8 MB) ----
  float* zreg  = (float*)d_ws;                       // 2*NB*DF f32 (src|tar)
  float* z_src = zreg;
  float* z_tar = zreg + (size_t)NB * DF;
  unsigned short* aggb = (unsigned short*)zreg;      // alias (dead before z)
  float* stats = zreg + (size_t)2 * NB * DF;         // 512
  float* mstd  = stats + 512;                        // 512
  float* dinv  = mstd + 512;                         // 50,048
  int* cnt  = (int*)(dinv + 50048);                  // 50,000
  int* fill = cnt + NN;                              // 50,000
  int* rp   = fill + NN;                             // 50,016
  int* perm = rp + 50016;                            // 600,000
  int* bsum = perm + 600000;                         // 256
  unsigned short* h_c = (unsigned short*)(bsum + 256);    // NN*DF u16
  unsigned short* h1b = h_c + (size_t)NN * DF;            // NN*DF u16
  unsigned short* h2b = h_c;                 // alias: h_c dead after layer 0
  unsigned short* WsB = h1b + (size_t)NN * DF;  // 2*DF*DF u16 (both layers)
  unsigned short* WnB = WsB + 2 * DF * DF;      // 2*DF*DF u16
  unsigned short* W1B = WnB + 2 * DF * DF;      // 3*DF*DF u16

  // zero-init + weight swizzle + h cast
  k_zero_i<<<(2 * NN + 255) / 256, 256, 0, stream>>>(cnt, 2 * NN);
  k_zero_f<<<2, 256, 0, stream>>>(stats, 512);
  k_prep<<<192, 256, 0, stream>>>(Wself, Wneigh, W1, WsB, WnB, W1B);
  k_cvt_h<<<(NN * DF / 8 + 255) / 256, 256, 0, stream>>>(h_in, h_c, NN * DF / 8);

  // CSR build (multi-block scan, deginv fused into scan3)
  k_hist<<<(NE + 255) / 256, 256, 0, stream>>>(edst, cnt);
  k_scan1<<<196, 256, 0, stream>>>(cnt, bsum);
  k_scan2<<<1, 256, 0, stream>>>(bsum);
  k_scan3<<<196, 256, 0, stream>>>(cnt, bsum, rp, dinv);
  k_scatter<<<(NE + 255) / 256, 256, 0, stream>>>(esrc, edst, rp, fill, perm);

  // SAGE layer 0: h_c -> h1b
  k_agg<<<(NN + 3) / 4, 256, 0, stream>>>((const unsigned int*)h_c, rp, perm,
                                          dinv, (unsigned int*)aggb);
  k_layer_mfma<<<(NN + 63) / 64, 256, 0, stream>>>(h_c, aggb, WsB, WnB, bconv, h1b);
  // SAGE layer 1: h1b -> h2b
  k_agg<<<(NN + 3) / 4, 256, 0, stream>>>((const unsigned int*)h1b, rp, perm,
                                          dinv, (unsigned int*)aggb);
  k_layer_mfma<<<(NN + 63) / 64, 256, 0, stream>>>(h1b, aggb, WsB + DF * DF,
                                                   WnB + DF * DF, bconv + DF, h2b);

  // head
  k_pair_mfma<<<NB / 64, 256, 0, stream>>>(h2b, x1, x2, W1B, b1, z_src);
  k_pair_mfma<<<NB / 64, 256, 0, stream>>>(h2b, x1t, x2t, W1B, b1, z_tar);
  k_colstats<<<dim3(256, 2), 128, 0, stream>>>(zreg, stats);
  k_finstats<<<1, 256, 0, stream>>>(stats, mstd);
  k_norm<<<dim3((NB * DF + 255) / 256, 2), 256, 0, stream>>>(zreg, mstd, gamma, beta, mmd_src);
  k_hp<<<NB, 128, 0, stream>>>(mmd_src, W2, b2, hp_out);
}

// Round 13
// 313.811 us; speedup vs baseline: 2.9230x; 1.0565x over previous
//
#include <hip/hip_runtime.h>

#define NN 50000   // nodes
#define NE 600000  // edges
#define DF 128     // features
#define NB 16384   // pair batch

typedef short bf16x8 __attribute__((ext_vector_type(8)));
typedef float f32x4 __attribute__((ext_vector_type(4)));

__device__ __forceinline__ float bf2f(unsigned short u){
  return __uint_as_float(((unsigned int)u) << 16);
}
__device__ __forceinline__ unsigned short f2bf(float x){
  unsigned int b = __float_as_uint(x);
  return (unsigned short)((b + 0x7FFFu + ((b >> 16) & 1u)) >> 16);
}

// Original template symbol (defined, never launched).
__global__ void GraphSAGE_8504035246140_kernel(){ }

// ---- fused prelude: h cast | zero cnt/fill | zero stats | weight swizzle ----
// grid 3710 x 256: [0,3125) cvt_h, [3125,3516) zero cnt+fill,
// [3516,3518) zero stats, [3518,3710) weight prep.
__global__ __launch_bounds__(256) void k_prelude(
    const float* h_in, unsigned short* h_c,
    const float* Ws, const float* Wn, const float* W1,
    unsigned short* WsB, unsigned short* WnB, unsigned short* W1B,
    int* cnt, float* stats){
  int b = blockIdx.x, t = threadIdx.x;
  if (b < 3125){                       // 3125*256 == NN*DF/8 exactly
    int i = b * 256 + t;
    const float4* s = (const float4*)h_in;
    float4 v0 = s[i * 2], v1 = s[i * 2 + 1];
    unsigned short d[8] = {f2bf(v0.x), f2bf(v0.y), f2bf(v0.z), f2bf(v0.w),
                           f2bf(v1.x), f2bf(v1.y), f2bf(v1.z), f2bf(v1.w)};
    *(bf16x8*)(h_c + i * 8) = *(bf16x8*)d;
  } else if (b < 3516){
    int i = (b - 3125) * 256 + t;
    if (i < 2 * NN) cnt[i] = 0;        // cnt + fill (adjacent)
  } else if (b < 3518){
    int i = (b - 3516) * 256 + t;
    if (i < 512) stats[i] = 0.f;
  } else {
    int idx = (b - 3518) * 256 + t;    // 192 blocks -> 49152 threads
    if (idx < 2 * DF * DF){
      int layer = idx >> 14;
      int e = idx & (DF * DF - 1);
      int k = e >> 7, n = e & 127;
      int dst = layer * DF * DF + (((k >> 3) * 128 + n) << 3) + (k & 7);
      WsB[dst] = f2bf(Ws[idx]);
      WnB[dst] = f2bf(Wn[idx]);
    }
    if (idx < 3 * DF * DF){
      int k = idx >> 7, n = idx & 127; // W1: 384x128
      W1B[(((k >> 3) * 128 + n) << 3) + (k & 7)] = f2bf(W1[idx]);
    }
  }
}

// ---- CSR build ----
__global__ void k_hist(const int* dst, int* cnt){
  int e = blockIdx.x * 256 + threadIdx.x;
  if (e < NE) atomicAdd(&cnt[dst[e]], 1);
}
__global__ void k_scan1(const int* cnt, int* bsum){   // grid 196
  __shared__ int l[256];
  int t = threadIdx.x, i = blockIdx.x * 256 + t;
  l[t] = (i < NN) ? cnt[i] : 0;
  __syncthreads();
  for (int o = 128; o > 0; o >>= 1){
    if (t < o) l[t] += l[t + o];
    __syncthreads();
  }
  if (t == 0) bsum[blockIdx.x] = l[0];
}
__global__ void k_scan2(int* bsum){                   // 1 block, inclusive
  __shared__ int l[256];
  int t = threadIdx.x;
  l[t] = (t < 196) ? bsum[t] : 0;
  __syncthreads();
  for (int o = 1; o < 256; o <<= 1){
    int v = (t >= o) ? l[t - o] : 0;
    __syncthreads();
    l[t] += v;
    __syncthreads();
  }
  bsum[t] = l[t];
}
__global__ void k_scan3(const int* cnt, const int* bsum, int* rp, float* dinv){
  __shared__ int l[256];
  int t = threadIdx.x, i = blockIdx.x * 256 + t;
  int v = (i < NN) ? cnt[i] : 0;
  l[t] = v;
  __syncthreads();
  for (int o = 1; o < 256; o <<= 1){
    int x = (t >= o) ? l[t - o] : 0;
    __syncthreads();
    l[t] += x;
    __syncthreads();
  }
  int base = (blockIdx.x == 0) ? 0 : bsum[blockIdx.x - 1];
  if (i < NN){
    rp[i] = base + l[t] - v;
    dinv[i] = 1.0f / fmaxf((float)v, 1.0f);
    if (i == NN - 1) rp[NN] = base + l[t];
  }
}
__global__ void k_scatter(const int* src, const int* dst,
                          const int* rp, int* fill, int* perm){
  int e = blockIdx.x * 256 + threadIdx.x;
  if (e < NE){
    int d = dst[e];
    int pos = atomicAdd(&fill[d], 1);
    perm[rp[d] + pos] = src[e];
  }
}

// ---- mean aggregation: one wave per node, 8-way unrolled ----
__global__ __launch_bounds__(256) void k_agg(
    const unsigned int* hb32, const int* rp, const int* perm,
    const float* dinv, unsigned int* agg32){
  int n = blockIdx.x * 4 + (threadIdx.x >> 6);
  if (n >= NN) return;
  int l = threadIdx.x & 63;
  int s = rp[n], e = rp[n + 1];
  float a0 = 0.f, a1 = 0.f, b0 = 0.f, b1 = 0.f;
  int i = s;
  for (; i + 8 <= e; i += 8){
    int u0 = perm[i],     u1 = perm[i + 1], u2 = perm[i + 2], u3 = perm[i + 3];
    int u4 = perm[i + 4], u5 = perm[i + 5], u6 = perm[i + 6], u7 = perm[i + 7];
    unsigned int x0 = hb32[(size_t)u0 * 64 + l];
    unsigned int x1 = hb32[(size_t)u1 * 64 + l];
    unsigned int x2 = hb32[(size_t)u2 * 64 + l];
    unsigned int x3 = hb32[(size_t)u3 * 64 + l];
    unsigned int x4 = hb32[(size_t)u4 * 64 + l];
    unsigned int x5 = hb32[(size_t)u5 * 64 + l];
    unsigned int x6 = hb32[(size_t)u6 * 64 + l];
    unsigned int x7 = hb32[(size_t)u7 * 64 + l];
    a0 += __uint_as_float(x0 << 16); a1 += __uint_as_float(x0 & 0xffff0000u);
    b0 += __uint_as_float(x1 << 16); b1 += __uint_as_float(x1 & 0xffff0000u);
    a0 += __uint_as_float(x2 << 16); a1 += __uint_as_float(x2 & 0xffff0000u);
    b0 += __uint_as_float(x3 << 16); b1 += __uint_as_float(x3 & 0xffff0000u);
    a0 += __uint_as_float(x4 << 16); a1 += __uint_as_float(x4 & 0xffff0000u);
    b0 += __uint_as_float(x5 << 16); b1 += __uint_as_float(x5 & 0xffff0000u);
    a0 += __uint_as_float(x6 << 16); a1 += __uint_as_float(x6 & 0xffff0000u);
    b0 += __uint_as_float(x7 << 16); b1 += __uint_as_float(x7 & 0xffff0000u);
  }
  for (; i < e; ++i){
    unsigned int u = hb32[(size_t)perm[i] * 64 + l];
    a0 += __uint_as_float(u << 16);
    a1 += __uint_as_float(u & 0xffff0000u);
  }
  a0 += b0; a1 += b1;
  float di = dinv[n];
  agg32[(size_t)n * 64 + l] =
      (unsigned int)f2bf(a0 * di) | ((unsigned int)f2bf(a1 * di) << 16);
}

// ---- layer GEMM via MFMA: hout = relu(h@Ws + agg@Wn + b) ----
__global__ __launch_bounds__(256) void k_layer_mfma(
    const unsigned short* hb, const unsigned short* aggb,
    const unsigned short* WsB, const unsigned short* WnB,
    const float* bias, unsigned short* hout){
  int t = threadIdx.x;
  int w = t >> 6, l = t & 63;
  int m = l & 15, q = l >> 4;
  int r0 = blockIdx.x * 64 + w * 16;
  int arow = r0 + m; if (arow > NN - 1) arow = NN - 1;
  const unsigned short* hp = hb   + (size_t)arow * DF + q * 8;
  const unsigned short* ap = aggb + (size_t)arow * DF + q * 8;
  f32x4 acc[8];
  for (int ct = 0; ct < 8; ++ct){
    float bbc = bias[ct * 16 + m];
    acc[ct] = (f32x4){bbc, bbc, bbc, bbc};
  }
  for (int kt = 0; kt < 4; ++kt){
    bf16x8 a_h = *(const bf16x8*)(hp + kt * 32);
    bf16x8 a_g = *(const bf16x8*)(ap + kt * 32);
    int kg = kt * 4 + q;
    for (int ct = 0; ct < 8; ++ct){
      bf16x8 b_s = *(const bf16x8*)(WsB + (((kg << 7) + ct * 16 + m) << 3));
      bf16x8 b_n = *(const bf16x8*)(WnB + (((kg << 7) + ct * 16 + m) << 3));
      acc[ct] = __builtin_amdgcn_mfma_f32_16x16x32_bf16(a_h, b_s, acc[ct], 0, 0, 0);
      acc[ct] = __builtin_amdgcn_mfma_f32_16x16x32_bf16(a_g, b_n, acc[ct], 0, 0, 0);
    }
  }
  for (int ct = 0; ct < 8; ++ct){
    int col = ct * 16 + m;
    for (int reg = 0; reg < 4; ++reg){
      int row = r0 + q * 4 + reg;
      if (row < NN) hout[(size_t)row * DF + col] = f2bf(fmaxf(acc[ct][reg], 0.f));
    }
  }
}

// ---- pair GEMM via MFMA + fused BN column stats; src/tar via blockIdx.y ----
__global__ __launch_bounds__(256) void k_pair_mfma(
    const unsigned short* h2,
    const int* x1, const int* x2, const int* x1t, const int* x2t,
    const unsigned short* W1B, const float* b1, float* zbase, float* stats){
  __shared__ __align__(16) unsigned short F[64 * 392];
  __shared__ float csum[128], csq[128];
  int g = blockIdx.y;
  const int* ia = g ? x1t : x1;
  const int* ib = g ? x2t : x2;
  float* z = zbase + (size_t)g * NB * DF;
  int t = threadIdx.x;
  if (t < 128){ csum[t] = 0.f; csq[t] = 0.f; }
  int r0 = blockIdx.x * 64;
  int i = t >> 2, qq = t & 3;
  int r = r0 + i;
  int a = ia[r], b = ib[r];
  const unsigned short* pa = h2 + (size_t)a * DF + qq * 32;
  const unsigned short* pb = h2 + (size_t)b * DF + qq * 32;
  unsigned short* fr = F + i * 392;
  for (int jj = 0; jj < 4; ++jj){
    bf16x8 va = *(const bf16x8*)(pa + jj * 8);
    bf16x8 vb = *(const bf16x8*)(pb + jj * 8);
    *(bf16x8*)(fr + qq * 32 + jj * 8) = va;
    *(bf16x8*)(fr + 128 + qq * 32 + jj * 8) = vb;
    unsigned short d[8];
    for (int e = 0; e < 8; ++e){
      float fa = bf2f((unsigned short)va[e]);
      float fb = bf2f((unsigned short)vb[e]);
      d[e] = f2bf(fabsf(fa - fb));
    }
    *(bf16x8*)(fr + 256 + qq * 32 + jj * 8) = *(bf16x8*)d;
  }
  __syncthreads();
  int w = t >> 6, l = t & 63;
  int m = l & 15, q = l >> 4;
  int rl = w * 16 + m;
  f32x4 acc[8];
  for (int ct = 0; ct < 8; ++ct){
    float bbc = b1[ct * 16 + m];
    acc[ct] = (f32x4){bbc, bbc, bbc, bbc};
  }
  for (int kt = 0; kt < 12; ++kt){
    bf16x8 af = *(const bf16x8*)(F + rl * 392 + kt * 32 + q * 8);
    int kg = kt * 4 + q;
    for (int ct = 0; ct < 8; ++ct){
      bf16x8 bfr = *(const bf16x8*)(W1B + (((kg << 7) + ct * 16 + m) << 3));
      acc[ct] = __builtin_amdgcn_mfma_f32_16x16x32_bf16(af, bfr, acc[ct], 0, 0, 0);
    }
  }
  for (int ct = 0; ct < 8; ++ct){
    int col = ct * 16 + m;
    int row = r0 + w * 16 + q * 4;
    float s = 0.f, s2 = 0.f;
    for (int reg = 0; reg < 4; ++reg){
      float v = acc[ct][reg];
      z[(size_t)(row + reg) * DF + col] = v;
      s += v; s2 += v * v;
    }
    atomicAdd(&csum[col], s);
    atomicAdd(&csq[col], s2);
  }
  __syncthreads();
  if (t < 128){
    atomicAdd(&stats[g * 256 + t], csum[t]);
    atomicAdd(&stats[g * 256 + 128 + t], csq[t]);
  }
}

// ---- fused BN-normalize + relu + (src only) h_p GEMM ----
// block = 2 rows x 128 cols; grid (NB/2, 2).
__global__ __launch_bounds__(256) void k_norm_hp(
    const float* zbase, const float* stats,
    const float* gamma, const float* beta,
    const float* W2, const float* b2, float* mmd_base, float* hp){
  __shared__ float s0[256], s1[256];
  int g = blockIdx.y;
  int t = threadIdx.x;
  int rl = t >> 7, c = t & 127;
  int row = blockIdx.x * 2 + rl;
  float m = stats[g * 256 + c] / (float)NB;
  float v = stats[g * 256 + 128 + c] / (float)NB - m * m;
  float istd = 1.0f / sqrtf(v + 1e-5f);
  size_t off = (size_t)g * NB * DF + (size_t)row * DF + c;
  float y = fmaxf((zbase[off] - m) * istd * gamma[c] + beta[c], 0.f);
  mmd_base[off] = y;
  if (g == 0){
    s0[t] = y * W2[c * 2];
    s1[t] = y * W2[c * 2 + 1];
    __syncthreads();
    int base = rl << 7;
    for (int o = 64; o > 0; o >>= 1){
      if (c < o){ s0[base + c] += s0[base + c + o]; s1[base + c] += s1[base + c + o]; }
      __syncthreads();
    }
    if (c == 0){
      hp[row * 2]     = s0[base] + b2[0];
      hp[row * 2 + 1] = s1[base] + b2[1];
    }
  }
}

extern "C" __attribute__((used, visibility("default")))
void kernel_launch(void* const* d_in, const int* in_sizes, int n_in,
                   void* d_out, int out_size, void* d_ws, size_t ws_size,
                   hipStream_t stream){
  const float* h_in  = (const float*)d_in[0];
  const int* esrc = (const int*)d_in[1];
  const int* edst = (const int*)d_in[2];
  const int* x1   = (const int*)d_in[3];
  const int* x2   = (const int*)d_in[4];
  const int* x1t  = (const int*)d_in[5];
  const int* x2t  = (const int*)d_in[6];
  const float* Wself = (const float*)d_in[7];
  const float* Wneigh= (const float*)d_in[8];
  const float* bconv = (const float*)d_in[9];
  const float* W1    = (const float*)d_in[10];
  const float* b1    = (const float*)d_in[11];
  const float* gamma = (const float*)d_in[12];
  const float* beta  = (const float*)d_in[13];
  const float* W2    = (const float*)d_in[14];
  const float* b2    = (const float*)d_in[15];
  float* out = (float*)d_out;                   // fp32 outputs
  float* hp_out   = out;                        // [NB,2]
  float* mmd_base = out + 2 * NB;               // [2][NB,DF] contiguous

  // ---- workspace layout (~45.8 MB) ----
  float* zreg  = (float*)d_ws;                       // 2*NB*DF f32 (src|tar)
  unsigned short* aggb = (unsigned short*)zreg;      // alias (dead before z)
  float* stats = zreg + (size_t)2 * NB * DF;         // 512
  float* mstd  = stats + 512;                        // 512 (unused, kept for layout)
  float* dinv  = mstd + 512;                         // 50,048
  int* cnt  = (int*)(dinv + 50048);                  // 50,000
  int* fill = cnt + NN;                              // 50,000
  int* rp   = fill + NN;                             // 50,016
  int* perm = rp + 50016;                            // 600,000
  int* bsum = perm + 600000;                         // 256
  unsigned short* h_c = (unsigned short*)(bsum + 256);    // NN*DF u16
  unsigned short* h1b = h_c + (size_t)NN * DF;            // NN*DF u16
  unsigned short* h2b = h_c;                 // alias: h_c dead after layer 0
  unsigned short* WsB = h1b + (size_t)NN * DF;  // 2*DF*DF u16 (both layers)
  unsigned short* WnB = WsB + 2 * DF * DF;      // 2*DF*DF u16
  unsigned short* W1B = WnB + 2 * DF * DF;      // 3*DF*DF u16

  // fused prelude: h cast + zeroing + weight swizzle
  k_prelude<<<3710, 256, 0, stream>>>(h_in, h_c, Wself, Wneigh, W1,
                                      WsB, WnB, W1B, cnt, stats);

  // CSR build
  k_hist<<<(NE + 255) / 256, 256, 0, stream>>>(edst, cnt);
  k_scan1<<<196, 256, 0, stream>>>(cnt, bsum);
  k_scan2<<<1, 256, 0, stream>>>(bsum);
  k_scan3<<<196, 256, 0, stream>>>(cnt, bsum, rp, dinv);
  k_scatter<<<(NE + 255) / 256, 256, 0, stream>>>(esrc, edst, rp, fill, perm);

  // SAGE layer 0: h_c -> h1b
  k_agg<<<(NN + 3) / 4, 256, 0, stream>>>((const unsigned int*)h_c, rp, perm,
                                          dinv, (unsigned int*)aggb);
  k_layer_mfma<<<(NN + 63) / 64, 256, 0, stream>>>(h_c, aggb, WsB, WnB, bconv, h1b);
  // SAGE layer 1: h1b -> h2b
  k_agg<<<(NN + 3) / 4, 256, 0, stream>>>((const unsigned int*)h1b, rp, perm,
                                          dinv, (unsigned int*)aggb);
  k_layer_mfma<<<(NN + 63) / 64, 256, 0, stream>>>(h1b, aggb, WsB + DF * DF,
                                                   WnB + DF * DF, bconv + DF, h2b);

  // head: pair GEMM (+ fused col-stats), then normalize (+ fused h_p)
  k_pair_mfma<<<dim3(NB / 64, 2), 256, 0, stream>>>(h2b, x1, x2, x1t, x2t,
                                                    W1B, b1, zreg, stats);
  k_norm_hp<<<dim3(NB / 2, 2), 256, 0, stream>>>(zreg, stats, gamma, beta,
                                                 W2, b2, mmd_base, hp_out);
}

// Round 14
// 301.762 us; speedup vs baseline: 3.0397x; 1.0399x over previous
//
#include <hip/hip_runtime.h>

#define NN 50000   // nodes
#define NE 600000  // edges
#define DF 128     // features
#define NB 16384   // pair batch

typedef short bf16x8 __attribute__((ext_vector_type(8)));
typedef float f32x4 __attribute__((ext_vector_type(4)));

__device__ __forceinline__ float bf2f(unsigned short u){
  return __uint_as_float(((unsigned int)u) << 16);
}
__device__ __forceinline__ unsigned short f2bf(float x){
  unsigned int b = __float_as_uint(x);
  return (unsigned short)((b + 0x7FFFu + ((b >> 16) & 1u)) >> 16);
}

// Original template symbol (defined, never launched).
__global__ void GraphSAGE_8504035246140_kernel(){ }

// ---- fused prelude: h cast | zero cnt/fill | zero stats | weight swizzle ----
__global__ __launch_bounds__(256) void k_prelude(
    const float* h_in, unsigned short* h_c,
    const float* Ws, const float* Wn, const float* W1,
    unsigned short* WsB, unsigned short* WnB, unsigned short* W1B,
    int* cnt, float* stats){
  int b = blockIdx.x, t = threadIdx.x;
  if (b < 3125){                       // 3125*256 == NN*DF/8 exactly
    int i = b * 256 + t;
    const float4* s = (const float4*)h_in;
    float4 v0 = s[i * 2], v1 = s[i * 2 + 1];
    unsigned short d[8] = {f2bf(v0.x), f2bf(v0.y), f2bf(v0.z), f2bf(v0.w),
                           f2bf(v1.x), f2bf(v1.y), f2bf(v1.z), f2bf(v1.w)};
    *(bf16x8*)(h_c + i * 8) = *(bf16x8*)d;
  } else if (b < 3516){
    int i = (b - 3125) * 256 + t;
    if (i < 2 * NN) cnt[i] = 0;        // cnt + fill (adjacent)
  } else if (b < 3518){
    int i = (b - 3516) * 256 + t;
    if (i < 512) stats[i] = 0.f;
  } else {
    int idx = (b - 3518) * 256 + t;    // 192 blocks -> 49152 threads
    if (idx < 2 * DF * DF){
      int layer = idx >> 14;
      int e = idx & (DF * DF - 1);
      int k = e >> 7, n = e & 127;
      int dst = layer * DF * DF + (((k >> 3) * 128 + n) << 3) + (k & 7);
      WsB[dst] = f2bf(Ws[idx]);
      WnB[dst] = f2bf(Wn[idx]);
    }
    if (idx < 3 * DF * DF){
      int k = idx >> 7, n = idx & 127; // W1: 384x128
      W1B[(((k >> 3) * 128 + n) << 3) + (k & 7)] = f2bf(W1[idx]);
    }
  }
}

// ---- CSR build ----
__global__ void k_hist(const int* dst, int* cnt){
  int e = blockIdx.x * 256 + threadIdx.x;
  if (e < NE) atomicAdd(&cnt[dst[e]], 1);
}
__global__ void k_scan1(const int* cnt, int* bsum){   // grid 196: block sums
  __shared__ int l[256];
  int t = threadIdx.x, i = blockIdx.x * 256 + t;
  l[t] = (i < NN) ? cnt[i] : 0;
  __syncthreads();
  for (int o = 128; o > 0; o >>= 1){
    if (t < o) l[t] += l[t + o];
    __syncthreads();
  }
  if (t == 0) bsum[blockIdx.x] = l[0];
}
// scan3: folds the global scan of bsum (196 values) into every block.
__global__ void k_scan3(const int* cnt, const int* bsum, int* rp, float* dinv){
  __shared__ int bs[256];
  __shared__ int l[256];
  int t = threadIdx.x, i = blockIdx.x * 256 + t;
  bs[t] = (t < 196) ? bsum[t] : 0;
  int v = (i < NN) ? cnt[i] : 0;
  l[t] = v;
  __syncthreads();
  for (int o = 1; o < 256; o <<= 1){
    int xb = (t >= o) ? bs[t - o] : 0;
    int xl = (t >= o) ? l[t - o] : 0;
    __syncthreads();
    bs[t] += xb; l[t] += xl;
    __syncthreads();
  }
  int base = (blockIdx.x == 0) ? 0 : bs[blockIdx.x - 1];
  if (i < NN){
    rp[i] = base + l[t] - v;
    dinv[i] = 1.0f / fmaxf((float)v, 1.0f);
    if (i == NN - 1) rp[NN] = base + l[t];
  }
}
__global__ void k_scatter(const int* src, const int* dst,
                          const int* rp, int* fill, int* perm){
  int e = blockIdx.x * 256 + threadIdx.x;
  if (e < NE){
    int d = dst[e];
    int pos = atomicAdd(&fill[d], 1);
    perm[rp[d] + pos] = src[e];
  }
}

// ---- mean aggregation: one wave per node, split-half uint2 gather ----
// Lanes 0-31 handle even edges, 32-63 odd edges; each lane loads 8 B (4 bf16
// columns). One wave instruction moves 512 B = 2 edge rows; 4 loads in flight
// cover 8 edges. Cross-half combine via shfl_xor(32).
__global__ __launch_bounds__(256) void k_agg(
    const unsigned int* hb32, const int* rp, const int* perm,
    const float* dinv, unsigned int* agg32){
  int n = blockIdx.x * 4 + (threadIdx.x >> 6);
  if (n >= NN) return;
  int l = threadIdx.x & 63;
  int half = l >> 5, lh = l & 31;
  int s = rp[n], e = rp[n + 1];
  float a0 = 0.f, a1 = 0.f, a2 = 0.f, a3 = 0.f;
  int i = s;
  for (; i + 8 <= e; i += 8){
    int p0 = perm[i + 0 + half];
    int p1 = perm[i + 2 + half];
    int p2 = perm[i + 4 + half];
    int p3 = perm[i + 6 + half];
    uint2 x0 = *(const uint2*)(hb32 + (size_t)p0 * 64 + lh * 2);
    uint2 x1 = *(const uint2*)(hb32 + (size_t)p1 * 64 + lh * 2);
    uint2 x2 = *(const uint2*)(hb32 + (size_t)p2 * 64 + lh * 2);
    uint2 x3 = *(const uint2*)(hb32 + (size_t)p3 * 64 + lh * 2);
    a0 += __uint_as_float(x0.x << 16); a1 += __uint_as_float(x0.x & 0xffff0000u);
    a2 += __uint_as_float(x0.y << 16); a3 += __uint_as_float(x0.y & 0xffff0000u);
    a0 += __uint_as_float(x1.x << 16); a1 += __uint_as_float(x1.x & 0xffff0000u);
    a2 += __uint_as_float(x1.y << 16); a3 += __uint_as_float(x1.y & 0xffff0000u);
    a0 += __uint_as_float(x2.x << 16); a1 += __uint_as_float(x2.x & 0xffff0000u);
    a2 += __uint_as_float(x2.y << 16); a3 += __uint_as_float(x2.y & 0xffff0000u);
    a0 += __uint_as_float(x3.x << 16); a1 += __uint_as_float(x3.x & 0xffff0000u);
    a2 += __uint_as_float(x3.y << 16); a3 += __uint_as_float(x3.y & 0xffff0000u);
  }
  for (; i < e; i += 2){
    if (i + half < e){
      int p = perm[i + half];
      uint2 x = *(const uint2*)(hb32 + (size_t)p * 64 + lh * 2);
      a0 += __uint_as_float(x.x << 16); a1 += __uint_as_float(x.x & 0xffff0000u);
      a2 += __uint_as_float(x.y << 16); a3 += __uint_as_float(x.y & 0xffff0000u);
    }
  }
  a0 += __shfl_xor(a0, 32);
  a1 += __shfl_xor(a1, 32);
  a2 += __shfl_xor(a2, 32);
  a3 += __shfl_xor(a3, 32);
  if (half == 0){
    float di = dinv[n];
    uint2 r;
    r.x = (unsigned int)f2bf(a0 * di) | ((unsigned int)f2bf(a1 * di) << 16);
    r.y = (unsigned int)f2bf(a2 * di) | ((unsigned int)f2bf(a3 * di) << 16);
    *(uint2*)(agg32 + (size_t)n * 64 + lh * 2) = r;
  }
}

// ---- layer GEMM via MFMA: hout = relu(h@Ws + agg@Wn + b) ----
__global__ __launch_bounds__(256) void k_layer_mfma(
    const unsigned short* hb, const unsigned short* aggb,
    const unsigned short* WsB, const unsigned short* WnB,
    const float* bias, unsigned short* hout){
  int t = threadIdx.x;
  int w = t >> 6, l = t & 63;
  int m = l & 15, q = l >> 4;
  int r0 = blockIdx.x * 64 + w * 16;
  int arow = r0 + m; if (arow > NN - 1) arow = NN - 1;
  const unsigned short* hp = hb   + (size_t)arow * DF + q * 8;
  const unsigned short* ap = aggb + (size_t)arow * DF + q * 8;
  f32x4 acc[8];
  for (int ct = 0; ct < 8; ++ct){
    float bbc = bias[ct * 16 + m];
    acc[ct] = (f32x4){bbc, bbc, bbc, bbc};
  }
  for (int kt = 0; kt < 4; ++kt){
    bf16x8 a_h = *(const bf16x8*)(hp + kt * 32);
    bf16x8 a_g = *(const bf16x8*)(ap + kt * 32);
    int kg = kt * 4 + q;
    for (int ct = 0; ct < 8; ++ct){
      bf16x8 b_s = *(const bf16x8*)(WsB + (((kg << 7) + ct * 16 + m) << 3));
      bf16x8 b_n = *(const bf16x8*)(WnB + (((kg << 7) + ct * 16 + m) << 3));
      acc[ct] = __builtin_amdgcn_mfma_f32_16x16x32_bf16(a_h, b_s, acc[ct], 0, 0, 0);
      acc[ct] = __builtin_amdgcn_mfma_f32_16x16x32_bf16(a_g, b_n, acc[ct], 0, 0, 0);
    }
  }
  for (int ct = 0; ct < 8; ++ct){
    int col = ct * 16 + m;
    for (int reg = 0; reg < 4; ++reg){
      int row = r0 + q * 4 + reg;
      if (row < NN) hout[(size_t)row * DF + col] = f2bf(fmaxf(acc[ct][reg], 0.f));
    }
  }
}

// ---- pair GEMM via MFMA + fused BN column stats; src/tar via blockIdx.y ----
__global__ __launch_bounds__(256) void k_pair_mfma(
    const unsigned short* h2,
    const int* x1, const int* x2, const int* x1t, const int* x2t,
    const unsigned short* W1B, const float* b1, float* zbase, float* stats){
  __shared__ __align__(16) unsigned short F[64 * 392];
  __shared__ float csum[128], csq[128];
  int g = blockIdx.y;
  const int* ia = g ? x1t : x1;
  const int* ib = g ? x2t : x2;
  float* z = zbase + (size_t)g * NB * DF;
  int t = threadIdx.x;
  if (t < 128){ csum[t] = 0.f; csq[t] = 0.f; }
  int r0 = blockIdx.x * 64;
  int i = t >> 2, qq = t & 3;
  int r = r0 + i;
  int a = ia[r], b = ib[r];
  const unsigned short* pa = h2 + (size_t)a * DF + qq * 32;
  const unsigned short* pb = h2 + (size_t)b * DF + qq * 32;
  unsigned short* fr = F + i * 392;
  for (int jj = 0; jj < 4; ++jj){
    bf16x8 va = *(const bf16x8*)(pa + jj * 8);
    bf16x8 vb = *(const bf16x8*)(pb + jj * 8);
    *(bf16x8*)(fr + qq * 32 + jj * 8) = va;
    *(bf16x8*)(fr + 128 + qq * 32 + jj * 8) = vb;
    unsigned short d[8];
    for (int e = 0; e < 8; ++e){
      float fa = bf2f((unsigned short)va[e]);
      float fb = bf2f((unsigned short)vb[e]);
      d[e] = f2bf(fabsf(fa - fb));
    }
    *(bf16x8*)(fr + 256 + qq * 32 + jj * 8) = *(bf16x8*)d;
  }
  __syncthreads();
  int w = t >> 6, l = t & 63;
  int m = l & 15, q = l >> 4;
  int rl = w * 16 + m;
  f32x4 acc[8];
  for (int ct = 0; ct < 8; ++ct){
    float bbc = b1[ct * 16 + m];
    acc[ct] = (f32x4){bbc, bbc, bbc, bbc};
  }
  for (int kt = 0; kt < 12; ++kt){
    bf16x8 af = *(const bf16x8*)(F + rl * 392 + kt * 32 + q * 8);
    int kg = kt * 4 + q;
    for (int ct = 0; ct < 8; ++ct){
      bf16x8 bfr = *(const bf16x8*)(W1B + (((kg << 7) + ct * 16 + m) << 3));
      acc[ct] = __builtin_amdgcn_mfma_f32_16x16x32_bf16(af, bfr, acc[ct], 0, 0, 0);
    }
  }
  for (int ct = 0; ct < 8; ++ct){
    int col = ct * 16 + m;
    int row = r0 + w * 16 + q * 4;
    float s = 0.f, s2 = 0.f;
    for (int reg = 0; reg < 4; ++reg){
      float v = acc[ct][reg];
      z[(size_t)(row + reg) * DF + col] = v;
      s += v; s2 += v * v;
    }
    atomicAdd(&csum[col], s);
    atomicAdd(&csq[col], s2);
  }
  __syncthreads();
  if (t < 128){
    atomicAdd(&stats[g * 256 + t], csum[t]);
    atomicAdd(&stats[g * 256 + 128 + t], csq[t]);
  }
}

// ---- fused BN-normalize + relu + (src only) h_p GEMM ----
__global__ __launch_bounds__(256) void k_norm_hp(
    const float* zbase, const float* stats,
    const float* gamma, const float* beta,
    const float* W2, const float* b2, float* mmd_base, float* hp){
  __shared__ float s0[256], s1[256];
  int g = blockIdx.y;
  int t = threadIdx.x;
  int rl = t >> 7, c = t & 127;
  int row = blockIdx.x * 2 + rl;
  float m = stats[g * 256 + c] / (float)NB;
  float v = stats[g * 256 + 128 + c] / (float)NB - m * m;
  float istd = 1.0f / sqrtf(v + 1e-5f);
  size_t off = (size_t)g * NB * DF + (size_t)row * DF + c;
  float y = fmaxf((zbase[off] - m) * istd * gamma[c] + beta[c], 0.f);
  mmd_base[off] = y;
  if (g == 0){
    s0[t] = y * W2[c * 2];
    s1[t] = y * W2[c * 2 + 1];
    __syncthreads();
    int base = rl << 7;
    for (int o = 64; o > 0; o >>= 1){
      if (c < o){ s0[base + c] += s0[base + c + o]; s1[base + c] += s1[base + c + o]; }
      __syncthreads();
    }
    if (c == 0){
      hp[row * 2]     = s0[base] + b2[0];
      hp[row * 2 + 1] = s1[base] + b2[1];
    }
  }
}

extern "C" __attribute__((used, visibility("default")))
void kernel_launch(void* const* d_in, const int* in_sizes, int n_in,
                   void* d_out, int out_size, void* d_ws, size_t ws_size,
                   hipStream_t stream){
  const float* h_in  = (const float*)d_in[0];
  const int* esrc = (const int*)d_in[1];
  const int* edst = (const int*)d_in[2];
  const int* x1   = (const int*)d_in[3];
  const int* x2   = (const int*)d_in[4];
  const int* x1t  = (const int*)d_in[5];
  const int* x2t  = (const int*)d_in[6];
  const float* Wself = (const float*)d_in[7];
  const float* Wneigh= (const float*)d_in[8];
  const float* bconv = (const float*)d_in[9];
  const float* W1    = (const float*)d_in[10];
  const float* b1    = (const float*)d_in[11];
  const float* gamma = (const float*)d_in[12];
  const float* beta  = (const float*)d_in[13];
  const float* W2    = (const float*)d_in[14];
  const float* b2    = (const float*)d_in[15];
  float* out = (float*)d_out;                   // fp32 outputs
  float* hp_out   = out;                        // [NB,2]
  float* mmd_base = out + 2 * NB;               // [2][NB,DF] contiguous

  // ---- workspace layout (~45.8 MB) ----
  float* zreg  = (float*)d_ws;                       // 2*NB*DF f32 (src|tar)
  unsigned short* aggb = (unsigned short*)zreg;      // alias (dead before z)
  float* stats = zreg + (size_t)2 * NB * DF;         // 512
  float* mstd  = stats + 512;                        // 512 (layout pad)
  float* dinv  = mstd + 512;                         // 50,048
  int* cnt  = (int*)(dinv + 50048);                  // 50,000
  int* fill = cnt + NN;                              // 50,000
  int* rp   = fill + NN;                             // 50,016
  int* perm = rp + 50016;                            // 600,000
  int* bsum = perm + 600000;                         // 256
  unsigned short* h_c = (unsigned short*)(bsum + 256);    // NN*DF u16
  unsigned short* h1b = h_c + (size_t)NN * DF;            // NN*DF u16
  unsigned short* h2b = h_c;                 // alias: h_c dead after layer 0
  unsigned short* WsB = h1b + (size_t)NN * DF;  // 2*DF*DF u16 (both layers)
  unsigned short* WnB = WsB + 2 * DF * DF;      // 2*DF*DF u16
  unsigned short* W1B = WnB + 2 * DF * DF;      // 3*DF*DF u16

  // fused prelude: h cast + zeroing + weight swizzle
  k_prelude<<<3710, 256, 0, stream>>>(h_in, h_c, Wself, Wneigh, W1,
                                      WsB, WnB, W1B, cnt, stats);

  // CSR build (scan2 folded into scan3)
  k_hist<<<(NE + 255) / 256, 256, 0, stream>>>(edst, cnt);
  k_scan1<<<196, 256, 0, stream>>>(cnt, bsum);
  k_scan3<<<196, 256, 0, stream>>>(cnt, bsum, rp, dinv);
  k_scatter<<<(NE + 255) / 256, 256, 0, stream>>>(esrc, edst, rp, fill, perm);

  // SAGE layer 0: h_c -> h1b
  k_agg<<<(NN + 3) / 4, 256, 0, stream>>>((const unsigned int*)h_c, rp, perm,
                                          dinv, (unsigned int*)aggb);
  k_layer_mfma<<<(NN + 63) / 64, 256, 0, stream>>>(h_c, aggb, WsB, WnB, bconv, h1b);
  // SAGE layer 1: h1b -> h2b
  k_agg<<<(NN + 3) / 4, 256, 0, stream>>>((const unsigned int*)h1b, rp, perm,
                                          dinv, (unsigned int*)aggb);
  k_layer_mfma<<<(NN + 63) / 64, 256, 0, stream>>>(h1b, aggb, WsB + DF * DF,
                                                   WnB + DF * DF, bconv + DF, h2b);

  // head: pair GEMM (+ fused col-stats), then normalize (+ fused h_p)
  k_pair_mfma<<<dim3(NB / 64, 2), 256, 0, stream>>>(h2b, x1, x2, x1t, x2t,
                                                    W1B, b1, zreg, stats);
  k_norm_hp<<<dim3(NB / 2, 2), 256, 0, stream>>>(zreg, stats, gamma, beta,
                                                 W2, b2, mmd_base, hp_out);
}